// Round 3
// baseline (2127.011 us; speedup 1.0000x reference)
//
#include <hip/hip_runtime.h>
#include <math.h>

#define VSZ 50000
#define HD 600
#define HHD 300
#define LATD 100
#define MLEN 50
#define TIN 48
#define TTGT 50
#define NBLK 75
#define NTHR 512
#define NTOT (NBLK*NTHR)

typedef __attribute__((ext_vector_type(4))) float f32x4;
typedef __attribute__((ext_vector_type(8))) short s16x8;

__device__ __forceinline__ double sigd(double x){ return 1.0/(1.0+exp(-x)); }

__device__ __forceinline__ void redu3d(double&a,double&b,double&c){
    #pragma unroll
    for(int off=32;off;off>>=1){
        a+=__shfl_xor(a,off); b+=__shfl_xor(b,off); c+=__shfl_xor(c,off);
    }
}
__device__ __forceinline__ void redu6d(double&a,double&b,double&c,double&d,double&e,double&f){
    #pragma unroll
    for(int off=32;off;off>>=1){
        a+=__shfl_xor(a,off); b+=__shfl_xor(b,off); c+=__shfl_xor(c,off);
        d+=__shfl_xor(d,off); e+=__shfl_xor(e,off); f+=__shfl_xor(f,off);
    }
}

// f32 x f32 -> f64 dot
__device__ __forceinline__ double dot64_ff(const float* __restrict__ a,
                                           const float* __restrict__ b, int n){
    double s0=0,s1=0,s2=0,s3=0;
    for(int k=0;k<n;k+=4){
        f32x4 av=*(const f32x4*)(a+k), bv=*(const f32x4*)(b+k);
        s0=fma((double)av[0],(double)bv[0],s0); s1=fma((double)av[1],(double)bv[1],s1);
        s2=fma((double)av[2],(double)bv[2],s2); s3=fma((double)av[3],(double)bv[3],s3);
    }
    return (s0+s1)+(s2+s3);
}
// f32 weights x f64 vector -> f64 dot
__device__ __forceinline__ double dot64_fd(const float* __restrict__ w,
                                           const double* __restrict__ x, int n){
    double s0=0,s1=0,s2=0,s3=0;
    for(int k=0;k<n;k+=4){
        f32x4 wv=*(const f32x4*)(w+k);
        s0=fma((double)wv[0],x[k],s0);   s1=fma((double)wv[1],x[k+1],s1);
        s2=fma((double)wv[2],x[k+2],s2); s3=fma((double)wv[3],x[k+3],s3);
    }
    return (s0+s1)+(s2+s3);
}

// monotonic-epoch grid barrier, agent scope (cross-XCD safe per G16)
__device__ __forceinline__ void gridbar(int* bar, int e){
    __syncthreads();
    if (threadIdx.x==0){
        __threadfence();
        int prev = __hip_atomic_fetch_add(&bar[0],1,__ATOMIC_RELAXED,__HIP_MEMORY_SCOPE_AGENT);
        if (prev == e*NBLK-1){
            __hip_atomic_store(&bar[1],e,__ATOMIC_RELAXED,__HIP_MEMORY_SCOPE_AGENT);
        } else {
            int s;
            do {
                __builtin_amdgcn_s_sleep(1);
                s = __hip_atomic_load(&bar[1],__ATOMIC_RELAXED,__HIP_MEMORY_SCOPE_AGENT);
            } while (s < e);
        }
        __threadfence();
    }
    __syncthreads();
}

__global__ void k_init(int* bar){
    if (threadIdx.x < 2) bar[threadIdx.x] = 0;
}

// Entire sequential pipeline in f64: pre-compute, encoder, latent, decoder.
__global__ void __launch_bounds__(NTHR) k_seq(
    const float* __restrict__ emb_enc, const float* __restrict__ emb_dec,
    const float* __restrict__ enc_wih_f, const float* __restrict__ enc_whh_f,
    const float* __restrict__ enc_bih_f, const float* __restrict__ enc_bhh_f,
    const float* __restrict__ enc_wih_b, const float* __restrict__ enc_whh_b,
    const float* __restrict__ enc_bih_b, const float* __restrict__ enc_bhh_b,
    const float* __restrict__ dec_wih_f, const float* __restrict__ dec_whh_f,
    const float* __restrict__ dec_bih_f, const float* __restrict__ dec_bhh_f,
    const float* __restrict__ dec_wih_b, const float* __restrict__ dec_whh_b,
    const float* __restrict__ dec_bih_b, const float* __restrict__ dec_bhh_b,
    const float* __restrict__ w_mean, const float* __restrict__ b_mean,
    const float* __restrict__ w_logv, const float* __restrict__ b_logv,
    const float* __restrict__ w_l2h, const float* __restrict__ b_l2h,
    const float* __restrict__ attn_w, const float* __restrict__ attn_b,
    const float* __restrict__ comb_w, const float* __restrict__ comb_b,
    const float* __restrict__ eps, const int* __restrict__ in_toks,
    const int* __restrict__ tgt_toks,
    double* __restrict__ GId, double* __restrict__ ENCd, double* __restrict__ Zd,
    double* __restrict__ LATd, double* __restrict__ Md, double* __restrict__ APREd,
    double* __restrict__ CPREd, double* __restrict__ HSd,
    double* __restrict__ MEANd, double* __restrict__ LOGVd,
    float* __restrict__ HSf,
    float* __restrict__ out_mean, float* __restrict__ out_logv,
    int* bar){

    __shared__ double h_lds[640];
    __shared__ double o_lds[640];
    __shared__ double s_lds[64];
    __shared__ double aw_lds[64];

    const int tid  = threadIdx.x;
    const int lane = tid & 63;
    const int wid  = tid >> 6;
    const int gtid = blockIdx.x*NTHR + tid;
    const int gw   = blockIdx.x*8 + wid;      // 0..599, exact
    const int dir  = gw / HHD;
    const int k    = gw % HHD;
    int ep = 0;

    if (tid < 40){ h_lds[600+tid]=0.0; o_lds[600+tid]=0.0; }

    // ---------------- PRE PHASE (parallel) ----------------
    if (gtid < (MLEN-TIN)*HD) ENCd[TIN*HD + gtid] = 0.0;
    for (int idx=gtid; idx<TIN*1800; idx+=NTOT){
        int t=idx/1800, r=idx%1800, d=r/900, j=r%900;
        const float* w  = d ? enc_wih_b : enc_wih_f;
        const float* bi = d ? enc_bih_b : enc_bih_f;
        const float* x  = emb_enc + (long)in_toks[t]*HD;
        GId[idx] = (double)bi[j] + dot64_ff(w + (long)j*HD, x, HD);
    }
    for (int idx=gtid; idx<TTGT*MLEN; idx+=NTOT){
        int t=idx/MLEN, a=idx%MLEN;
        int tok = t ? tgt_toks[t-1] : 1;
        APREd[idx] = (double)attn_b[a] + dot64_ff(attn_w + (long)a*1200, emb_dec + (long)tok*HD, HD);
    }
    for (int idx=gtid; idx<TTGT*HD; idx+=NTOT){
        int t=idx/HD, j=idx%HD;
        int tok = t ? tgt_toks[t-1] : 1;
        CPREd[idx] = (double)comb_b[j] + dot64_ff(comb_w + (long)j*1200, emb_dec + (long)tok*HD, HD);
    }
    gridbar(bar, ++ep);

    // ---------------- ENCODER (48 steps, 1 barrier each) ----------------
    {
        const float* whh = dir ? enc_whh_b : enc_whh_f;
        const float* bhh = dir ? enc_bhh_b : enc_bhh_f;
        float wr_[5], wz_[5], wn_[5];
        #pragma unroll
        for (int i=0;i<5;i++){
            int k2 = lane + 64*i;
            bool ok = k2 < HHD;
            wr_[i] = ok ? whh[(long)k*HHD + k2] : 0.f;
            wz_[i] = ok ? whh[(long)(HHD+k)*HHD + k2] : 0.f;
            wn_[i] = ok ? whh[(long)(2*HHD+k)*HHD + k2] : 0.f;
        }
        const double bhr = (double)bhh[k], bhz = (double)bhh[HHD+k], bhn = (double)bhh[2*HHD+k];
        // per-lane GI preload: lane t holds step t's 3 gi values
        double gr=0, gz=0, gn=0;
        if (lane < TIN){
            const double* g = GId + (long)lane*1800 + dir*900;
            gr = g[k]; gz = g[HHD+k]; gn = g[2*HHD+k];
        }
        for (int t=0; t<TIN; t++){
            if (tid < HD) h_lds[tid] = t ? ENCd[(long)(t-1)*HD + tid] : 0.0;
            __syncthreads();
            double sr=0, sz=0, sn=0;
            #pragma unroll
            for (int i=0;i<5;i++){
                double hv = h_lds[dir*HHD + lane + 64*i];
                sr = fma((double)wr_[i], hv, sr);
                sz = fma((double)wz_[i], hv, sz);
                sn = fma((double)wn_[i], hv, sn);
            }
            redu3d(sr, sz, sn);
            double grt=__shfl(gr,t), gzt=__shfl(gz,t), gnt=__shfl(gn,t);
            if (lane==0){
                double r = sigd(grt + sr + bhr);
                double z = sigd(gzt + sz + bhz);
                double n = tanh(gnt + r*(sn + bhn));
                double hp = h_lds[dir*HHD + k];
                ENCd[(long)t*HD + dir*HHD + k] = (1.0-z)*n + z*hp;
            }
            gridbar(bar, ++ep);
        }
    }

    // ---------------- LATENT (parallel phases) ----------------
    for (int idx=gtid; idx<2*MLEN*LATD; idx+=NTOT){
        int which=idx/(MLEN*LATD), rem=idx%(MLEN*LATD), i=rem/LATD, l=rem%LATD;
        const float* W = which ? w_logv : w_mean;
        const float* B = which ? b_logv : b_mean;
        double v = (double)B[l] + dot64_fd(W + (long)l*HD, ENCd + (long)i*HD, HD);
        if (which){ LOGVd[rem]=v; out_logv[rem]=(float)v; }
        else      { MEANd[rem]=v; out_mean[rem]=(float)v; }
    }
    gridbar(bar, ++ep);
    for (int idx=gtid; idx<MLEN*LATD; idx+=NTOT)
        Zd[idx] = (double)eps[idx]*exp(0.5*LOGVd[idx]) + MEANd[idx];
    gridbar(bar, ++ep);
    for (int idx=gtid; idx<MLEN*HD; idx+=NTOT){
        int i=idx/HD, j=idx%HD;
        LATd[idx] = (double)b_l2h[j] + dot64_fd(w_l2h + (long)j*LATD, Zd + (long)i*LATD, LATD);
    }
    gridbar(bar, ++ep);
    for (int idx=gtid; idx<MLEN*HD; idx+=NTOT){
        int i=idx/HD, j=idx%HD;          // M layout [i][j] for coalesced o-loop
        Md[idx] = dot64_fd(comb_w + (long)j*1200 + HD, LATd + (long)i*HD, HD);
    }
    gridbar(bar, ++ep);

    // ---------------- DECODER (50 steps, 1 barrier each) ----------------
    {
        const float* wih = dir ? dec_wih_b : dec_wih_f;
        const float* bih = dir ? dec_bih_b : dec_bih_f;
        const float* whh = dir ? dec_whh_b : dec_whh_f;
        const float* bhh = dir ? dec_bhh_b : dec_bhh_f;
        float ur[10], uz[10], un[10];
        #pragma unroll
        for (int i=0;i<10;i++){
            int k2 = lane + 64*i;
            bool ok = k2 < HD;
            ur[i] = ok ? wih[(long)k*HD + k2] : 0.f;
            uz[i] = ok ? wih[(long)(HHD+k)*HD + k2] : 0.f;
            un[i] = ok ? wih[(long)(2*HHD+k)*HD + k2] : 0.f;
        }
        float vr[5], vz[5], vn[5];
        #pragma unroll
        for (int i=0;i<5;i++){
            int k2 = lane + 64*i;
            bool ok = k2 < HHD;
            vr[i] = ok ? whh[(long)k*HHD + k2] : 0.f;
            vz[i] = ok ? whh[(long)(HHD+k)*HHD + k2] : 0.f;
            vn[i] = ok ? whh[(long)(2*HHD+k)*HHD + k2] : 0.f;
        }
        const double bir = (double)bih[k], biz = (double)bih[HHD+k], bin_ = (double)bih[2*HHD+k];
        const double bhr = (double)bhh[k], bhz = (double)bhh[HHD+k], bhn = (double)bhh[2*HHD+k];

        for (int t=0; t<TTGT; t++){
            const double* hp = t ? (HSd + (long)(t-1)*HD) : (ENCd + (long)(TIN-1)*HD);
            if (tid < HD) h_lds[tid] = hp[tid];
            __syncthreads();
            // --- phase A (replicated per block): attention scores ---
            for (int a=wid; a<MLEN; a+=8){
                const float* arow = attn_w + (long)a*1200 + HD;
                double acc = 0.0;
                #pragma unroll
                for (int i=0;i<10;i++){
                    int kk = lane + 64*i;
                    if (kk < HD) acc = fma((double)arow[kk], h_lds[kk], acc);
                }
                #pragma unroll
                for (int off=32;off;off>>=1) acc += __shfl_xor(acc,off);
                if (lane==0) s_lds[a] = acc + APREd[t*MLEN + a];
            }
            __syncthreads();
            // softmax (wave 0)
            if (wid==0){
                double v = (lane<MLEN) ? s_lds[lane] : -1e300;
                double m = v;
                #pragma unroll
                for (int off=32;off;off>>=1) m = fmax(m, __shfl_xor(m,off));
                double e = (lane<MLEN) ? exp(v-m) : 0.0;
                double ssum = e;
                #pragma unroll
                for (int off=32;off;off>>=1) ssum += __shfl_xor(ssum,off);
                if (lane<MLEN) aw_lds[lane] = e/ssum;
            }
            __syncthreads();
            // o = relu(CPRE + M^T aw)
            for (int j=tid; j<HD; j+=NTHR){
                double acc = CPREd[(long)t*HD + j];
                #pragma unroll
                for (int i=0;i<MLEN;i++) acc = fma(Md[i*HD + j], aw_lds[i], acc);
                o_lds[j] = fmax(acc, 0.0);
            }
            __syncthreads();
            // --- phase B: GRU cells ---
            double ar=0,az=0,an=0, hr=0,hz=0,hn=0;
            #pragma unroll
            for (int i=0;i<10;i++){
                double ov = o_lds[lane + 64*i];
                ar = fma((double)ur[i], ov, ar);
                az = fma((double)uz[i], ov, az);
                an = fma((double)un[i], ov, an);
            }
            #pragma unroll
            for (int i=0;i<5;i++){
                double hv = h_lds[dir*HHD + lane + 64*i];
                hr = fma((double)vr[i], hv, hr);
                hz = fma((double)vz[i], hv, hz);
                hn = fma((double)vn[i], hv, hn);
            }
            redu6d(ar,az,an,hr,hz,hn);
            if (lane==0){
                double r = sigd(ar + bir + hr + bhr);
                double zg = sigd(az + biz + hz + bhz);
                double n = tanh(an + bin_ + r*(hn + bhn));
                double hnew = (1.0-zg)*n + zg*h_lds[dir*HHD + k];
                HSd[(long)t*HD + dir*HHD + k] = hnew;
                HSf[(long)t*HD + dir*HHD + k] = (float)hnew;
            }
            gridbar(bar, ++ep);
        }
    }
}

// ---------------- vocab projection: bf16 MFMA, fused f32->bf16 ----------------
__device__ __forceinline__ s16x8 pack8(const float* __restrict__ p){
    s16x8 r;
    #pragma unroll
    for (int i=0;i<8;i++){
        unsigned u = __float_as_uint(p[i]);
        r[i] = (short)((u + 0x7fffu + ((u>>16)&1u)) >> 16);
    }
    return r;
}

__global__ void __launch_bounds__(256) k_vocab(const float* __restrict__ out_w,
        const float* __restrict__ out_b, const float* __restrict__ HS,
        float* __restrict__ logits){
    int lane = threadIdx.x & 63, wid = threadIdx.x >> 6;
    int vbase = blockIdx.x*64 + wid*16;
    int arow  = vbase + (lane & 15);
    int kg    = (lane >> 4) * 8;
    bool aok  = arow < VSZ;
    const float* ap = out_w + (long)(aok ? arow : 0) * HD;
    int t0 = lane & 15;
    f32x4 acc0 = {0,0,0,0}, acc1 = acc0, acc2 = acc0, acc3 = acc0;
    const s16x8 zf = (s16x8)0;

    for (int ks=0; ks<19; ks++){
        int kb = ks*32 + kg;
        bool kok = kb < HD;
        s16x8 a = (aok && kok) ? pack8(ap + kb) : zf;
        s16x8 b0 = kok              ? pack8(HS + (long)(t0     )*HD + kb) : zf;
        s16x8 b1 = kok              ? pack8(HS + (long)(t0 + 16)*HD + kb) : zf;
        s16x8 b2 = kok              ? pack8(HS + (long)(t0 + 32)*HD + kb) : zf;
        s16x8 b3 = (kok && t0 < 2)  ? pack8(HS + (long)(t0 + 48)*HD + kb) : zf;
        acc0 = __builtin_amdgcn_mfma_f32_16x16x32_bf16(a, b0, acc0, 0,0,0);
        acc1 = __builtin_amdgcn_mfma_f32_16x16x32_bf16(a, b1, acc1, 0,0,0);
        acc2 = __builtin_amdgcn_mfma_f32_16x16x32_bf16(a, b2, acc2, 0,0,0);
        acc3 = __builtin_amdgcn_mfma_f32_16x16x32_bf16(a, b3, acc3, 0,0,0);
    }

    int vst = vbase + (lane>>4)*4;
    float bb[4];
    #pragma unroll
    for (int r=0;r<4;r++) bb[r] = (vst+r < VSZ) ? out_b[vst+r] : 0.f;
    #pragma unroll
    for (int f=0; f<4; f++){
        int t = t0 + 16*f;
        if (t >= TTGT) continue;
        const f32x4 acc = f==0?acc0 : f==1?acc1 : f==2?acc2 : acc3;
        float* rowp = logits + (long)t*VSZ;
        #pragma unroll
        for (int r=0;r<4;r++){
            int v = vst + r;
            if (v < VSZ) rowp[v] = acc[r] + bb[r];
        }
    }
}

// in-place log-softmax per step row
__global__ void __launch_bounds__(1024) k_lsm(float* __restrict__ logits){
    __shared__ float red[16];
    __shared__ float sm, sl;
    long t = blockIdx.x;
    float* row = logits + t*VSZ;
    int tid = threadIdx.x, lane = tid&63, w = tid>>6;
    float m = -1e30f;
    for (int v=tid; v<VSZ; v+=1024) m = fmaxf(m, row[v]);
    #pragma unroll
    for (int off=32;off;off>>=1) m = fmaxf(m, __shfl_xor(m,off));
    if (lane==0) red[w] = m;
    __syncthreads();
    if (tid==0){ float mm=red[0]; for (int i=1;i<16;i++) mm=fmaxf(mm,red[i]); sm=mm; }
    __syncthreads();
    float mx = sm;
    float s = 0.f;
    for (int v=tid; v<VSZ; v+=1024) s += __expf(row[v]-mx);
    #pragma unroll
    for (int off=32;off;off>>=1) s += __shfl_xor(s,off);
    __syncthreads();
    if (lane==0) red[w] = s;
    __syncthreads();
    if (tid==0){ float ss=0.f; for (int i=0;i<16;i++) ss+=red[i]; sl = logf(ss); }
    __syncthreads();
    float lg = sl;
    for (int v=tid; v<VSZ; v+=1024) row[v] = row[v] - mx - lg;
}

extern "C" void kernel_launch(void* const* d_in, const int* in_sizes, int n_in,
                              void* d_out, int out_size, void* d_ws, size_t ws_size,
                              hipStream_t stream) {
    const float* emb_enc   = (const float*)d_in[0];
    const float* emb_dec   = (const float*)d_in[1];
    const float* enc_wih_f = (const float*)d_in[2];
    const float* enc_whh_f = (const float*)d_in[3];
    const float* enc_bih_f = (const float*)d_in[4];
    const float* enc_bhh_f = (const float*)d_in[5];
    const float* enc_wih_b = (const float*)d_in[6];
    const float* enc_whh_b = (const float*)d_in[7];
    const float* enc_bih_b = (const float*)d_in[8];
    const float* enc_bhh_b = (const float*)d_in[9];
    const float* dec_wih_f = (const float*)d_in[10];
    const float* dec_whh_f = (const float*)d_in[11];
    const float* dec_bih_f = (const float*)d_in[12];
    const float* dec_bhh_f = (const float*)d_in[13];
    const float* dec_wih_b = (const float*)d_in[14];
    const float* dec_whh_b = (const float*)d_in[15];
    const float* dec_bih_b = (const float*)d_in[16];
    const float* dec_bhh_b = (const float*)d_in[17];
    const float* w_mean    = (const float*)d_in[18];
    const float* b_mean    = (const float*)d_in[19];
    const float* w_logv    = (const float*)d_in[20];
    const float* b_logv    = (const float*)d_in[21];
    const float* w_l2h     = (const float*)d_in[22];
    const float* b_l2h     = (const float*)d_in[23];
    const float* attn_w    = (const float*)d_in[24];
    const float* attn_b    = (const float*)d_in[25];
    const float* comb_w    = (const float*)d_in[26];
    const float* comb_b    = (const float*)d_in[27];
    const float* out_w     = (const float*)d_in[28];
    const float* out_b     = (const float*)d_in[29];
    const float* eps       = (const float*)d_in[30];
    const int*   in_toks   = (const int*)d_in[31];
    const int*   tgt_toks  = (const int*)d_in[32];

    double* ws   = (double*)d_ws;
    double* GId   = ws;               // 86400
    double* ENCd  = ws + 86400;       // 30000
    double* Zd    = ws + 116400;      // 5000
    double* LATd  = ws + 121400;      // 30000
    double* Md    = ws + 151400;      // 30000 ([i][j])
    double* APREd = ws + 181400;      // 2500
    double* CPREd = ws + 183900;      // 30000
    double* HSd   = ws + 213904;      // 30000
    double* MEANd = ws + 243904;      // 5000
    double* LOGVd = ws + 248904;      // 5000
    float*  HSf   = (float*)(ws + 253904);  // 30000 floats
    int*    bar   = (int*)(ws + 268912);

    float* dec_out  = (float*)d_out;
    float* out_mean = dec_out + 2500000;
    float* out_logv = dec_out + 2505000;

    k_init<<<1, 64, 0, stream>>>(bar);

    k_seq<<<NBLK, NTHR, 0, stream>>>(
        emb_enc, emb_dec,
        enc_wih_f, enc_whh_f, enc_bih_f, enc_bhh_f,
        enc_wih_b, enc_whh_b, enc_bih_b, enc_bhh_b,
        dec_wih_f, dec_whh_f, dec_bih_f, dec_bhh_f,
        dec_wih_b, dec_whh_b, dec_bih_b, dec_bhh_b,
        w_mean, b_mean, w_logv, b_logv, w_l2h, b_l2h,
        attn_w, attn_b, comb_w, comb_b,
        eps, in_toks, tgt_toks,
        GId, ENCd, Zd, LATd, Md, APREd, CPREd, HSd, MEANd, LOGVd, HSf,
        out_mean, out_logv, bar);

    k_vocab<<<(VSZ + 63)/64, 256, 0, stream>>>(out_w, out_b, HSf, dec_out);
    k_lsm<<<TTGT, 1024, 0, stream>>>(dec_out);
}

// Round 4
// 1378.132 us; speedup vs baseline: 1.5434x; 1.5434x over previous
//
#include <hip/hip_runtime.h>
#include <math.h>

#define VSZ 50000
#define HD 600
#define HHD 300
#define LATD 100
#define MLEN 50
#define TIN 48
#define TTGT 50
#define NBLK 75
#define NTHR 512
#define NTOT (NBLK*NTHR)
#define ESTR 640              // padded row stride (2560B = 20 cache lines)
#define SLOT_STRIDE 32        // ints; 128B between slots

typedef __attribute__((ext_vector_type(4))) float f32x4;
typedef __attribute__((ext_vector_type(8))) short s16x8;

__device__ __forceinline__ float sigf(float x){ return 1.0f/(1.0f+__expf(-x)); }

// agent-scope (coherent-point) store/load: bypass non-coherent L2s, no fences
__device__ __forceinline__ void stf(float* p, float v){
    __hip_atomic_store((unsigned int*)p, __float_as_uint(v),
                       __ATOMIC_RELAXED, __HIP_MEMORY_SCOPE_AGENT);
}
__device__ __forceinline__ float ldf(const float* p){
    unsigned u = __hip_atomic_load((const unsigned int*)p,
                                   __ATOMIC_RELAXED, __HIP_MEMORY_SCOPE_AGENT);
    return __uint_as_float(u);
}
__device__ __forceinline__ int ldslot(const int* p){
    return __hip_atomic_load(p, __ATOMIC_RELAXED, __HIP_MEMORY_SCOPE_AGENT);
}

__device__ __forceinline__ void redu3(float&a,float&b,float&c){
    #pragma unroll
    for(int off=32;off;off>>=1){
        a+=__shfl_xor(a,off); b+=__shfl_xor(b,off); c+=__shfl_xor(c,off);
    }
}
__device__ __forceinline__ void redu6(float&a,float&b,float&c,float&d,float&e,float&f){
    #pragma unroll
    for(int off=32;off;off>>=1){
        a+=__shfl_xor(a,off); b+=__shfl_xor(b,off); c+=__shfl_xor(c,off);
        d+=__shfl_xor(d,off); e+=__shfl_xor(e,off); f+=__shfl_xor(f,off);
    }
}

// all-report grid barrier: no atomics contention, no threadfence.
// Every wave drains its (sc1) stores; block rep posts its slot; all blocks
// poll all slots (one thread per slot). Monotonic epochs; slots reset by k_init.
__device__ __forceinline__ void gridbar(int* slots, int e){
    asm volatile("s_waitcnt vmcnt(0)" ::: "memory");
    __syncthreads();
    int tid = threadIdx.x;
    if (tid == 0){
        __hip_atomic_store(&slots[blockIdx.x*SLOT_STRIDE], e,
                           __ATOMIC_RELAXED, __HIP_MEMORY_SCOPE_AGENT);
    }
    if (tid < NBLK){
        while (ldslot(&slots[tid*SLOT_STRIDE]) < e)
            __builtin_amdgcn_s_sleep(1);
    }
    __syncthreads();
}

__global__ void k_init(int* slots){
    int i = blockIdx.x*blockDim.x + threadIdx.x;
    if (i < NBLK*SLOT_STRIDE) slots[i] = 0;
}

__global__ void __launch_bounds__(NTHR) k_seq(
    const float* __restrict__ emb_enc, const float* __restrict__ emb_dec,
    const float* __restrict__ enc_wih_f, const float* __restrict__ enc_whh_f,
    const float* __restrict__ enc_bih_f, const float* __restrict__ enc_bhh_f,
    const float* __restrict__ enc_wih_b, const float* __restrict__ enc_whh_b,
    const float* __restrict__ enc_bih_b, const float* __restrict__ enc_bhh_b,
    const float* __restrict__ dec_wih_f, const float* __restrict__ dec_whh_f,
    const float* __restrict__ dec_bih_f, const float* __restrict__ dec_bhh_f,
    const float* __restrict__ dec_wih_b, const float* __restrict__ dec_whh_b,
    const float* __restrict__ dec_bih_b, const float* __restrict__ dec_bhh_b,
    const float* __restrict__ w_mean, const float* __restrict__ b_mean,
    const float* __restrict__ w_logv, const float* __restrict__ b_logv,
    const float* __restrict__ w_l2h, const float* __restrict__ b_l2h,
    const float* __restrict__ attn_w, const float* __restrict__ attn_b,
    const float* __restrict__ comb_w, const float* __restrict__ comb_b,
    const float* __restrict__ eps, const int* __restrict__ in_toks,
    const int* __restrict__ tgt_toks,
    float* __restrict__ GIf, float* __restrict__ ENCf,
    float* __restrict__ MEANf, float* __restrict__ LOGVf,
    float* __restrict__ Zf, float* __restrict__ LATf, float* __restrict__ Mf,
    float* __restrict__ APREf, float* __restrict__ CPREf,
    float* __restrict__ HSs, float* __restrict__ HSv,
    float* __restrict__ out_mean, float* __restrict__ out_logv,
    int* slots){

    __shared__ float h_lds[ESTR];
    __shared__ float o_lds[ESTR];
    __shared__ float s_lds[64];
    __shared__ float aw_lds[64];

    const int tid  = threadIdx.x;
    const int lane = tid & 63;
    const int wid  = tid >> 6;
    const int gtid = blockIdx.x*NTHR + tid;
    const int gw   = blockIdx.x*8 + wid;      // 0..599
    const int dir  = gw / HHD;
    const int k    = gw % HHD;
    int ep = 0;

    if (tid < ESTR-HD){ h_lds[HD+tid]=0.f; o_lds[HD+tid]=0.f; }

    // ---------------- PRE PHASE ----------------
    // zero padded ENC rows 48,49 (incl. padding)
    if (gtid < (MLEN-TIN)*ESTR) stf(&ENCf[TIN*ESTR + gtid], 0.f);
    // GI: R1-exact bias-seeded single fmaf chain
    for (int idx=gtid; idx<TIN*1800; idx+=NTOT){
        int t=idx/1800, r=idx%1800, d=r/900, j=r%900;
        const float* w  = d ? enc_wih_b : enc_wih_f;
        const float* bi = d ? enc_bih_b : enc_bih_f;
        const float* x  = emb_enc + (long)in_toks[t]*HD;
        const float* wr = w + (long)j*HD;
        float acc = bi[j];
        for (int kk=0;kk<HD;kk+=4){
            float4 wv = *(const float4*)(wr+kk);
            float4 xv = *(const float4*)(x+kk);
            acc = fmaf(wv.x,xv.x,acc); acc = fmaf(wv.y,xv.y,acc);
            acc = fmaf(wv.z,xv.z,acc); acc = fmaf(wv.w,xv.w,acc);
        }
        stf(&GIf[idx], acc);
    }
    for (int idx=gtid; idx<TTGT*MLEN; idx+=NTOT){
        int t=idx/MLEN, a=idx%MLEN;
        int tok = t ? tgt_toks[t-1] : 1;
        const float* x  = emb_dec + (long)tok*HD;
        const float* wr = attn_w + (long)a*1200;
        float acc = attn_b[a];
        for (int kk=0;kk<HD;kk+=4){
            float4 wv = *(const float4*)(wr+kk);
            float4 xv = *(const float4*)(x+kk);
            acc = fmaf(wv.x,xv.x,acc); acc = fmaf(wv.y,xv.y,acc);
            acc = fmaf(wv.z,xv.z,acc); acc = fmaf(wv.w,xv.w,acc);
        }
        stf(&APREf[idx], acc);
    }
    for (int idx=gtid; idx<TTGT*HD; idx+=NTOT){
        int t=idx/HD, j=idx%HD;
        int tok = t ? tgt_toks[t-1] : 1;
        const float* x  = emb_dec + (long)tok*HD;
        const float* wr = comb_w + (long)j*1200;
        float acc = comb_b[j];
        for (int kk=0;kk<HD;kk+=4){
            float4 wv = *(const float4*)(wr+kk);
            float4 xv = *(const float4*)(x+kk);
            acc = fmaf(wv.x,xv.x,acc); acc = fmaf(wv.y,xv.y,acc);
            acc = fmaf(wv.z,xv.z,acc); acc = fmaf(wv.w,xv.w,acc);
        }
        stf(&CPREf[idx], acc);
    }
    gridbar(slots, ++ep);

    // ---------------- ENCODER ----------------
    {
        const float* whh = dir ? enc_whh_b : enc_whh_f;
        const float* bhh = dir ? enc_bhh_b : enc_bhh_f;
        float wr_[5], wz_[5], wn_[5];
        #pragma unroll
        for (int i=0;i<5;i++){
            int k2 = lane + 64*i;
            bool ok = k2 < HHD;
            wr_[i] = ok ? whh[(long)k*HHD + k2] : 0.f;
            wz_[i] = ok ? whh[(long)(HHD+k)*HHD + k2] : 0.f;
            wn_[i] = ok ? whh[(long)(2*HHD+k)*HHD + k2] : 0.f;
        }
        const float bhr = bhh[k], bhz = bhh[HHD+k], bhn = bhh[2*HHD+k];
        float gr=0, gz=0, gn=0;
        if (lane < TIN){
            const float* g = GIf + (long)lane*1800 + dir*900;
            gr = ldf(g+k); gz = ldf(g+HHD+k); gn = ldf(g+2*HHD+k);
        }
        for (int t=0; t<TIN; t++){
            for (int j=tid; j<HD; j+=NTHR)
                h_lds[j] = t ? ldf(&ENCf[(long)(t-1)*ESTR + j]) : 0.f;
            __syncthreads();
            float sr=0, sz=0, sn=0;
            #pragma unroll
            for (int i=0;i<5;i++){
                float hv = h_lds[dir*HHD + lane + 64*i];
                sr = fmaf(wr_[i], hv, sr);
                sz = fmaf(wz_[i], hv, sz);
                sn = fmaf(wn_[i], hv, sn);
            }
            redu3(sr, sz, sn);
            float grt=__shfl(gr,t), gzt=__shfl(gz,t), gnt=__shfl(gn,t);
            if (lane==0){
                float r = sigf(grt + sr + bhr);
                float z = sigf(gzt + sz + bhz);
                float n = tanhf(gnt + r*(sn + bhn));
                float hp = h_lds[dir*HHD + k];
                stf(&ENCf[(long)t*ESTR + dir*HHD + k], (1.f-z)*n + z*hp);
            }
            gridbar(slots, ++ep);
        }
    }

    // ---------------- LATENT ----------------
    for (int idx=gtid; idx<2*MLEN*LATD; idx+=NTOT){
        int which=idx/(MLEN*LATD), rem=idx%(MLEN*LATD), i=rem/LATD, l=rem%LATD;
        const float* W = which ? w_logv : w_mean;
        const float* B = which ? b_logv : b_mean;
        const float* e = ENCf + (long)i*ESTR;
        const float* wr = W + (long)l*HD;
        float acc = B[l];
        for (int kk=0;kk<HD;kk+=4){
            float4 wv = *(const float4*)(wr+kk);
            acc = fmaf(wv.x, ldf(e+kk  ), acc); acc = fmaf(wv.y, ldf(e+kk+1), acc);
            acc = fmaf(wv.z, ldf(e+kk+2), acc); acc = fmaf(wv.w, ldf(e+kk+3), acc);
        }
        if (which){ stf(&LOGVf[rem], acc); out_logv[rem] = acc; }
        else      { stf(&MEANf[rem], acc); out_mean[rem] = acc; }
    }
    gridbar(slots, ++ep);
    for (int idx=gtid; idx<MLEN*LATD; idx+=NTOT)
        stf(&Zf[idx], eps[idx]*__expf(0.5f*ldf(&LOGVf[idx])) + ldf(&MEANf[idx]));
    gridbar(slots, ++ep);
    for (int idx=gtid; idx<MLEN*HD; idx+=NTOT){
        int i=idx/HD, j=idx%HD;
        const float* zr = Zf + (long)i*LATD;
        const float* wr = w_l2h + (long)j*LATD;
        float acc = b_l2h[j];
        for (int kk=0;kk<LATD;kk+=4){
            float4 wv = *(const float4*)(wr+kk);
            acc = fmaf(wv.x, ldf(zr+kk  ), acc); acc = fmaf(wv.y, ldf(zr+kk+1), acc);
            acc = fmaf(wv.z, ldf(zr+kk+2), acc); acc = fmaf(wv.w, ldf(zr+kk+3), acc);
        }
        stf(&LATf[idx], acc);
    }
    gridbar(slots, ++ep);
    for (int idx=gtid; idx<MLEN*HD; idx+=NTOT){
        int i=idx/HD, j=idx%HD;          // Mf layout [i][j]
        const float* wr = comb_w + (long)j*1200 + HD;
        const float* lr = LATf + (long)i*HD;
        float acc = 0.f;
        for (int kk=0;kk<HD;kk+=4){
            float4 wv = *(const float4*)(wr+kk);
            acc = fmaf(wv.x, ldf(lr+kk  ), acc); acc = fmaf(wv.y, ldf(lr+kk+1), acc);
            acc = fmaf(wv.z, ldf(lr+kk+2), acc); acc = fmaf(wv.w, ldf(lr+kk+3), acc);
        }
        stf(&Mf[idx], acc);
    }
    gridbar(slots, ++ep);

    // ---------------- DECODER ----------------
    {
        const float* wih = dir ? dec_wih_b : dec_wih_f;
        const float* bih = dir ? dec_bih_b : dec_bih_f;
        const float* whh = dir ? dec_whh_b : dec_whh_f;
        const float* bhh = dir ? dec_bhh_b : dec_bhh_f;
        float ur[10], uz[10], un[10];
        #pragma unroll
        for (int i=0;i<10;i++){
            int k2 = lane + 64*i;
            bool ok = k2 < HD;
            ur[i] = ok ? wih[(long)k*HD + k2] : 0.f;
            uz[i] = ok ? wih[(long)(HHD+k)*HD + k2] : 0.f;
            un[i] = ok ? wih[(long)(2*HHD+k)*HD + k2] : 0.f;
        }
        float vr[5], vz[5], vn[5];
        #pragma unroll
        for (int i=0;i<5;i++){
            int k2 = lane + 64*i;
            bool ok = k2 < HHD;
            vr[i] = ok ? whh[(long)k*HHD + k2] : 0.f;
            vz[i] = ok ? whh[(long)(HHD+k)*HHD + k2] : 0.f;
            vn[i] = ok ? whh[(long)(2*HHD+k)*HHD + k2] : 0.f;
        }
        const float bir = bih[k], biz = bih[HHD+k], bin_ = bih[2*HHD+k];
        const float bhr = bhh[k], bhz = bhh[HHD+k], bhn = bhh[2*HHD+k];

        for (int t=0; t<TTGT; t++){
            const float* hp = t ? (HSs + (long)(t-1)*ESTR) : (ENCf + (long)(TIN-1)*ESTR);
            for (int j=tid; j<HD; j+=NTHR) h_lds[j] = ldf(hp+j);
            __syncthreads();
            // attention scores (replicated per block)
            for (int a=wid; a<MLEN; a+=8){
                const float* arow = attn_w + (long)a*1200 + HD;
                float acc = 0.f;
                #pragma unroll
                for (int i=0;i<10;i++){
                    int kk = lane + 64*i;
                    if (kk < HD) acc = fmaf(arow[kk], h_lds[kk], acc);
                }
                #pragma unroll
                for (int off=32;off;off>>=1) acc += __shfl_xor(acc,off);
                if (lane==0) s_lds[a] = acc + ldf(&APREf[t*MLEN + a]);
            }
            __syncthreads();
            // softmax — R1-exact serial form (one thread)
            if (tid==0){
                float m = -1e30f;
                for (int a=0;a<MLEN;a++) m = fmaxf(m, s_lds[a]);
                float sum = 0.f;
                for (int a=0;a<MLEN;a++){ float e = __expf(s_lds[a]-m); aw_lds[a]=e; sum+=e; }
                float inv = 1.f/sum;
                for (int a=0;a<MLEN;a++) aw_lds[a] *= inv;
            }
            __syncthreads();
            // o = relu(CPRE + M^T aw)  (Mf plain/cached: write-once, read post-barrier)
            for (int j=tid; j<HD; j+=NTHR){
                float acc = ldf(&CPREf[(long)t*HD + j]);
                #pragma unroll
                for (int i=0;i<MLEN;i++) acc = fmaf(Mf[i*HD + j], aw_lds[i], acc);
                o_lds[j] = fmaxf(acc, 0.f);
            }
            __syncthreads();
            // GRU cells
            float ar=0,az=0,an=0, hr=0,hz=0,hn=0;
            #pragma unroll
            for (int i=0;i<10;i++){
                float ov = o_lds[lane + 64*i];
                ar = fmaf(ur[i], ov, ar);
                az = fmaf(uz[i], ov, az);
                an = fmaf(un[i], ov, an);
            }
            #pragma unroll
            for (int i=0;i<5;i++){
                float hv = h_lds[dir*HHD + lane + 64*i];
                hr = fmaf(vr[i], hv, hr);
                hz = fmaf(vz[i], hv, hz);
                hn = fmaf(vn[i], hv, hn);
            }
            redu6(ar,az,an,hr,hz,hn);
            if (lane==0){
                float r = sigf(ar + bir + hr + bhr);
                float zg = sigf(az + biz + hz + bhz);
                float n = tanhf(an + bin_ + r*(hn + bhn));
                float hnew = (1.f-zg)*n + zg*h_lds[dir*HHD + k];
                stf(&HSs[(long)t*ESTR + dir*HHD + k], hnew);
                HSv[(long)t*HD + dir*HHD + k] = hnew;   // for k_vocab (next kernel)
            }
            if (t < TTGT-1) gridbar(slots, ++ep);
        }
    }
}

// ---------------- vocab projection: bf16 MFMA, fused f32->bf16 ----------------
__device__ __forceinline__ s16x8 pack8(const float* __restrict__ p){
    s16x8 r;
    #pragma unroll
    for (int i=0;i<8;i++){
        unsigned u = __float_as_uint(p[i]);
        r[i] = (short)((u + 0x7fffu + ((u>>16)&1u)) >> 16);
    }
    return r;
}

__global__ void __launch_bounds__(256) k_vocab(const float* __restrict__ out_w,
        const float* __restrict__ out_b, const float* __restrict__ HS,
        float* __restrict__ logits){
    int lane = threadIdx.x & 63, wid = threadIdx.x >> 6;
    int vbase = blockIdx.x*64 + wid*16;
    int arow  = vbase + (lane & 15);
    int kg    = (lane >> 4) * 8;
    bool aok  = arow < VSZ;
    const float* ap = out_w + (long)(aok ? arow : 0) * HD;
    int t0 = lane & 15;
    f32x4 acc0 = {0,0,0,0}, acc1 = acc0, acc2 = acc0, acc3 = acc0;
    const s16x8 zf = (s16x8)0;

    for (int ks=0; ks<19; ks++){
        int kb = ks*32 + kg;
        bool kok = kb < HD;
        s16x8 a = (aok && kok) ? pack8(ap + kb) : zf;
        s16x8 b0 = kok              ? pack8(HS + (long)(t0     )*HD + kb) : zf;
        s16x8 b1 = kok              ? pack8(HS + (long)(t0 + 16)*HD + kb) : zf;
        s16x8 b2 = kok              ? pack8(HS + (long)(t0 + 32)*HD + kb) : zf;
        s16x8 b3 = (kok && t0 < 2)  ? pack8(HS + (long)(t0 + 48)*HD + kb) : zf;
        acc0 = __builtin_amdgcn_mfma_f32_16x16x32_bf16(a, b0, acc0, 0,0,0);
        acc1 = __builtin_amdgcn_mfma_f32_16x16x32_bf16(a, b1, acc1, 0,0,0);
        acc2 = __builtin_amdgcn_mfma_f32_16x16x32_bf16(a, b2, acc2, 0,0,0);
        acc3 = __builtin_amdgcn_mfma_f32_16x16x32_bf16(a, b3, acc3, 0,0,0);
    }

    int vst = vbase + (lane>>4)*4;
    float bb[4];
    #pragma unroll
    for (int r=0;r<4;r++) bb[r] = (vst+r < VSZ) ? out_b[vst+r] : 0.f;
    #pragma unroll
    for (int f=0; f<4; f++){
        int t = t0 + 16*f;
        if (t >= TTGT) continue;
        const f32x4 acc = f==0?acc0 : f==1?acc1 : f==2?acc2 : acc3;
        float* rowp = logits + (long)t*VSZ;
        #pragma unroll
        for (int r=0;r<4;r++){
            int v = vst + r;
            if (v < VSZ) rowp[v] = acc[r] + bb[r];
        }
    }
}

// in-place log-softmax per step row
__global__ void __launch_bounds__(1024) k_lsm(float* __restrict__ logits){
    __shared__ float red[16];
    __shared__ float sm, sl;
    long t = blockIdx.x;
    float* row = logits + t*VSZ;
    int tid = threadIdx.x, lane = tid&63, w = tid>>6;
    float m = -1e30f;
    for (int v=tid; v<VSZ; v+=1024) m = fmaxf(m, row[v]);
    #pragma unroll
    for (int off=32;off;off>>=1) m = fmaxf(m, __shfl_xor(m,off));
    if (lane==0) red[w] = m;
    __syncthreads();
    if (tid==0){ float mm=red[0]; for (int i=1;i<16;i++) mm=fmaxf(mm,red[i]); sm=mm; }
    __syncthreads();
    float mx = sm;
    float s = 0.f;
    for (int v=tid; v<VSZ; v+=1024) s += __expf(row[v]-mx);
    #pragma unroll
    for (int off=32;off;off>>=1) s += __shfl_xor(s,off);
    __syncthreads();
    if (lane==0) red[w] = s;
    __syncthreads();
    if (tid==0){ float ss=0.f; for (int i=0;i<16;i++) ss+=red[i]; sl = logf(ss); }
    __syncthreads();
    float lg = sl;
    for (int v=tid; v<VSZ; v+=1024) row[v] = row[v] - mx - lg;
}

extern "C" void kernel_launch(void* const* d_in, const int* in_sizes, int n_in,
                              void* d_out, int out_size, void* d_ws, size_t ws_size,
                              hipStream_t stream) {
    const float* emb_enc   = (const float*)d_in[0];
    const float* emb_dec   = (const float*)d_in[1];
    const float* enc_wih_f = (const float*)d_in[2];
    const float* enc_whh_f = (const float*)d_in[3];
    const float* enc_bih_f = (const float*)d_in[4];
    const float* enc_bhh_f = (const float*)d_in[5];
    const float* enc_wih_b = (const float*)d_in[6];
    const float* enc_whh_b = (const float*)d_in[7];
    const float* enc_bih_b = (const float*)d_in[8];
    const float* enc_bhh_b = (const float*)d_in[9];
    const float* dec_wih_f = (const float*)d_in[10];
    const float* dec_whh_f = (const float*)d_in[11];
    const float* dec_bih_f = (const float*)d_in[12];
    const float* dec_bhh_f = (const float*)d_in[13];
    const float* dec_wih_b = (const float*)d_in[14];
    const float* dec_whh_b = (const float*)d_in[15];
    const float* dec_bih_b = (const float*)d_in[16];
    const float* dec_bhh_b = (const float*)d_in[17];
    const float* w_mean    = (const float*)d_in[18];
    const float* b_mean    = (const float*)d_in[19];
    const float* w_logv    = (const float*)d_in[20];
    const float* b_logv    = (const float*)d_in[21];
    const float* w_l2h     = (const float*)d_in[22];
    const float* b_l2h     = (const float*)d_in[23];
    const float* attn_w    = (const float*)d_in[24];
    const float* attn_b    = (const float*)d_in[25];
    const float* comb_w    = (const float*)d_in[26];
    const float* comb_b    = (const float*)d_in[27];
    const float* out_w     = (const float*)d_in[28];
    const float* out_b     = (const float*)d_in[29];
    const float* eps       = (const float*)d_in[30];
    const int*   in_toks   = (const int*)d_in[31];
    const int*   tgt_toks  = (const int*)d_in[32];

    float* ws = (float*)d_ws;                  // all offsets 128B-aligned
    float* GIf   = ws;                         // 48*1800 = 86400
    float* ENCf  = ws + 86400;                 // 50*640  = 32000
    float* MEANf = ws + 118400;                // 5024
    float* LOGVf = ws + 123424;                // 5024
    float* Zf    = ws + 128448;                // 5024
    float* LATf  = ws + 133472;                // 30016
    float* Mf    = ws + 163488;                // 30016 ([i][j], stride 600)
    float* APREf = ws + 193504;                // 2528
    float* CPREf = ws + 196032;                // 30016
    float* HSs   = ws + 226048;                // 50*640 = 32000 (padded state)
    float* HSv   = ws + 258048;                // 50*600 = 30016 (for k_vocab)
    int*   slots = (int*)(ws + 288064);        // 75*32 ints

    float* dec_out  = (float*)d_out;
    float* out_mean = dec_out + 2500000;
    float* out_logv = dec_out + 2505000;

    k_init<<<(NBLK*SLOT_STRIDE + 255)/256, 256, 0, stream>>>(slots);

    k_seq<<<NBLK, NTHR, 0, stream>>>(
        emb_enc, emb_dec,
        enc_wih_f, enc_whh_f, enc_bih_f, enc_bhh_f,
        enc_wih_b, enc_whh_b, enc_bih_b, enc_bhh_b,
        dec_wih_f, dec_whh_f, dec_bih_f, dec_bhh_f,
        dec_wih_b, dec_whh_b, dec_bih_b, dec_bhh_b,
        w_mean, b_mean, w_logv, b_logv, w_l2h, b_l2h,
        attn_w, attn_b, comb_w, comb_b,
        eps, in_toks, tgt_toks,
        GIf, ENCf, MEANf, LOGVf, Zf, LATf, Mf, APREf, CPREf, HSs, HSv,
        out_mean, out_logv, slots);

    k_vocab<<<(VSZ + 63)/64, 256, 0, stream>>>(out_w, out_b, HSv, dec_out);
    k_lsm<<<TTGT, 1024, 0, stream>>>(dec_out);
}

// Round 5
// 1103.224 us; speedup vs baseline: 1.9280x; 1.2492x over previous
//
#include <hip/hip_runtime.h>
#include <math.h>

#define VSZ 50000
#define HD 600
#define HHD 300
#define LATD 100
#define MLEN 50
#define TIN 48
#define TTGT 50
#define NBLK 75
#define NTHR 512
#define NTOT (NBLK*NTHR)
#define ESTR 640              // padded row stride (2560B = 20 cache lines)
#define SLOT_STRIDE 32        // ints; 128B between slots

typedef __attribute__((ext_vector_type(4))) float f32x4;
typedef __attribute__((ext_vector_type(8))) short s16x8;

__device__ __forceinline__ float sigf(float x){ return 1.0f/(1.0f+__expf(-x)); }

// agent-scope (coherent-point) store/load: bypass non-coherent L2s
__device__ __forceinline__ void stf(float* p, float v){
    __hip_atomic_store((unsigned int*)p, __float_as_uint(v),
                       __ATOMIC_RELAXED, __HIP_MEMORY_SCOPE_AGENT);
}
__device__ __forceinline__ float ldf(const float* p){
    unsigned u = __hip_atomic_load((const unsigned int*)p,
                                   __ATOMIC_RELAXED, __HIP_MEMORY_SCOPE_AGENT);
    return __uint_as_float(u);
}
__device__ __forceinline__ int ldslot(const int* p){
    return __hip_atomic_load(p, __ATOMIC_RELAXED, __HIP_MEMORY_SCOPE_AGENT);
}
__device__ __forceinline__ void stslot(int* p, int v){
    __hip_atomic_store(p, v, __ATOMIC_RELAXED, __HIP_MEMORY_SCOPE_AGENT);
}

__device__ __forceinline__ void redu3(float&a,float&b,float&c){
    #pragma unroll
    for(int off=32;off;off>>=1){
        a+=__shfl_xor(a,off); b+=__shfl_xor(b,off); c+=__shfl_xor(c,off);
    }
}
__device__ __forceinline__ void redu6(float&a,float&b,float&c,float&d,float&e,float&f){
    #pragma unroll
    for(int off=32;off;off>>=1){
        a+=__shfl_xor(a,off); b+=__shfl_xor(b,off); c+=__shfl_xor(c,off);
        d+=__shfl_xor(d,off); e+=__shfl_xor(e,off); f+=__shfl_xor(f,off);
    }
}

// Two-level leader barrier: every cache line has exactly ONE writer and ONE
// poller (no same-line contention at the coherent point).
//  1) each block posts slots[bid] = e
//  2) block 0: lane i polls slots[i] (1 client/line); syncthreads;
//     lane i stores flags[i] = e (replicated release)
//  3) block b!=0: one thread polls flags[b] (1 client/line)
__device__ __forceinline__ void gridbar(int* slots, int* flags, int e){
    asm volatile("s_waitcnt vmcnt(0)" ::: "memory");
    __syncthreads();
    const int tid = threadIdx.x;
    if (tid == 0) stslot(&slots[blockIdx.x*SLOT_STRIDE], e);
    if (blockIdx.x == 0){
        if (tid < NBLK){
            while (ldslot(&slots[tid*SLOT_STRIDE]) < e)
                __builtin_amdgcn_s_sleep(1);
        }
        __syncthreads();
        if (tid < NBLK) stslot(&flags[tid*SLOT_STRIDE], e);
    } else {
        if (tid == 0){
            while (ldslot(&flags[blockIdx.x*SLOT_STRIDE]) < e)
                __builtin_amdgcn_s_sleep(1);
        }
    }
    __syncthreads();
}

__global__ void k_init(int* sync_mem){
    int i = blockIdx.x*blockDim.x + threadIdx.x;
    if (i < 2*NBLK*SLOT_STRIDE) sync_mem[i] = 0;
}

__global__ void __launch_bounds__(NTHR) k_seq(
    const float* __restrict__ emb_enc, const float* __restrict__ emb_dec,
    const float* __restrict__ enc_wih_f, const float* __restrict__ enc_whh_f,
    const float* __restrict__ enc_bih_f, const float* __restrict__ enc_bhh_f,
    const float* __restrict__ enc_wih_b, const float* __restrict__ enc_whh_b,
    const float* __restrict__ enc_bih_b, const float* __restrict__ enc_bhh_b,
    const float* __restrict__ dec_wih_f, const float* __restrict__ dec_whh_f,
    const float* __restrict__ dec_bih_f, const float* __restrict__ dec_bhh_f,
    const float* __restrict__ dec_wih_b, const float* __restrict__ dec_whh_b,
    const float* __restrict__ dec_bih_b, const float* __restrict__ dec_bhh_b,
    const float* __restrict__ w_mean, const float* __restrict__ b_mean,
    const float* __restrict__ w_logv, const float* __restrict__ b_logv,
    const float* __restrict__ w_l2h, const float* __restrict__ b_l2h,
    const float* __restrict__ attn_w, const float* __restrict__ attn_b,
    const float* __restrict__ comb_w, const float* __restrict__ comb_b,
    const float* __restrict__ eps, const int* __restrict__ in_toks,
    const int* __restrict__ tgt_toks,
    float* __restrict__ GIf, float* __restrict__ ENCf,
    float* __restrict__ MEANf, float* __restrict__ LOGVf,
    float* __restrict__ Zf, float* __restrict__ LATf, float* __restrict__ Mf,
    float* __restrict__ APREf, float* __restrict__ CPREf,
    float* __restrict__ HSs, float* __restrict__ HSv,
    float* __restrict__ out_mean, float* __restrict__ out_logv,
    int* slots, int* flags){

    __shared__ float h_lds[ESTR];
    __shared__ float o_lds[ESTR];
    __shared__ float s_lds[64];
    __shared__ float aw_lds[64];
    __shared__ float mf_lds[HD*MLEN];   // 120 KB: Mf[j][i], resident all decoder steps

    const int tid  = threadIdx.x;
    const int lane = tid & 63;
    const int wid  = tid >> 6;
    const int gtid = blockIdx.x*NTHR + tid;
    const int gw   = blockIdx.x*8 + wid;      // 0..599
    const int dir  = gw / HHD;
    const int k    = gw % HHD;
    int ep = 0;

    if (tid < ESTR-HD){ h_lds[HD+tid]=0.f; o_lds[HD+tid]=0.f; }

    // ---------------- PRE PHASE ----------------
    if (gtid < (MLEN-TIN)*ESTR) stf(&ENCf[TIN*ESTR + gtid], 0.f);
    // GI: R1-exact bias-seeded single fmaf chain
    for (int idx=gtid; idx<TIN*1800; idx+=NTOT){
        int t=idx/1800, r=idx%1800, d=r/900, j=r%900;
        const float* w  = d ? enc_wih_b : enc_wih_f;
        const float* bi = d ? enc_bih_b : enc_bih_f;
        const float* x  = emb_enc + (long)in_toks[t]*HD;
        const float* wr = w + (long)j*HD;
        float acc = bi[j];
        for (int kk=0;kk<HD;kk+=4){
            float4 wv = *(const float4*)(wr+kk);
            float4 xv = *(const float4*)(x+kk);
            acc = fmaf(wv.x,xv.x,acc); acc = fmaf(wv.y,xv.y,acc);
            acc = fmaf(wv.z,xv.z,acc); acc = fmaf(wv.w,xv.w,acc);
        }
        stf(&GIf[idx], acc);
    }
    for (int idx=gtid; idx<TTGT*MLEN; idx+=NTOT){
        int t=idx/MLEN, a=idx%MLEN;
        int tok = t ? tgt_toks[t-1] : 1;
        const float* x  = emb_dec + (long)tok*HD;
        const float* wr = attn_w + (long)a*1200;
        float acc = attn_b[a];
        for (int kk=0;kk<HD;kk+=4){
            float4 wv = *(const float4*)(wr+kk);
            float4 xv = *(const float4*)(x+kk);
            acc = fmaf(wv.x,xv.x,acc); acc = fmaf(wv.y,xv.y,acc);
            acc = fmaf(wv.z,xv.z,acc); acc = fmaf(wv.w,xv.w,acc);
        }
        stf(&APREf[idx], acc);
    }
    for (int idx=gtid; idx<TTGT*HD; idx+=NTOT){
        int t=idx/HD, j=idx%HD;
        int tok = t ? tgt_toks[t-1] : 1;
        const float* x  = emb_dec + (long)tok*HD;
        const float* wr = comb_w + (long)j*1200;
        float acc = comb_b[j];
        for (int kk=0;kk<HD;kk+=4){
            float4 wv = *(const float4*)(wr+kk);
            float4 xv = *(const float4*)(x+kk);
            acc = fmaf(wv.x,xv.x,acc); acc = fmaf(wv.y,xv.y,acc);
            acc = fmaf(wv.z,xv.z,acc); acc = fmaf(wv.w,xv.w,acc);
        }
        stf(&CPREf[idx], acc);
    }
    gridbar(slots, flags, ++ep);

    // ---------------- ENCODER ----------------
    {
        const float* whh = dir ? enc_whh_b : enc_whh_f;
        const float* bhh = dir ? enc_bhh_b : enc_bhh_f;
        float wr_[5], wz_[5], wn_[5];
        #pragma unroll
        for (int i=0;i<5;i++){
            int k2 = lane + 64*i;
            bool ok = k2 < HHD;
            wr_[i] = ok ? whh[(long)k*HHD + k2] : 0.f;
            wz_[i] = ok ? whh[(long)(HHD+k)*HHD + k2] : 0.f;
            wn_[i] = ok ? whh[(long)(2*HHD+k)*HHD + k2] : 0.f;
        }
        const float bhr = bhh[k], bhz = bhh[HHD+k], bhn = bhh[2*HHD+k];
        float gr=0, gz=0, gn=0;
        if (lane < TIN){
            const float* g = GIf + (long)lane*1800 + dir*900;
            gr = ldf(g+k); gz = ldf(g+HHD+k); gn = ldf(g+2*HHD+k);
        }
        for (int t=0; t<TIN; t++){
            for (int j=tid; j<HD; j+=NTHR)
                h_lds[j] = t ? ldf(&ENCf[(long)(t-1)*ESTR + j]) : 0.f;
            __syncthreads();
            float sr=0, sz=0, sn=0;
            #pragma unroll
            for (int i=0;i<5;i++){
                float hv = h_lds[dir*HHD + lane + 64*i];
                sr = fmaf(wr_[i], hv, sr);
                sz = fmaf(wz_[i], hv, sz);
                sn = fmaf(wn_[i], hv, sn);
            }
            redu3(sr, sz, sn);
            float grt=__shfl(gr,t), gzt=__shfl(gz,t), gnt=__shfl(gn,t);
            if (lane==0){
                float r = sigf(grt + sr + bhr);
                float z = sigf(gzt + sz + bhz);
                float n = tanhf(gnt + r*(sn + bhn));
                float hp = h_lds[dir*HHD + k];
                stf(&ENCf[(long)t*ESTR + dir*HHD + k], (1.f-z)*n + z*hp);
            }
            gridbar(slots, flags, ++ep);
        }
    }

    // ---------------- LATENT ----------------
    for (int idx=gtid; idx<2*MLEN*LATD; idx+=NTOT){
        int which=idx/(MLEN*LATD), rem=idx%(MLEN*LATD), i=rem/LATD, l=rem%LATD;
        const float* W = which ? w_logv : w_mean;
        const float* B = which ? b_logv : b_mean;
        const float* e = ENCf + (long)i*ESTR;
        const float* wr = W + (long)l*HD;
        float acc = B[l];
        for (int kk=0;kk<HD;kk+=4){
            float4 wv = *(const float4*)(wr+kk);
            acc = fmaf(wv.x, ldf(e+kk  ), acc); acc = fmaf(wv.y, ldf(e+kk+1), acc);
            acc = fmaf(wv.z, ldf(e+kk+2), acc); acc = fmaf(wv.w, ldf(e+kk+3), acc);
        }
        if (which){ stf(&LOGVf[rem], acc); out_logv[rem] = acc; }
        else      { stf(&MEANf[rem], acc); out_mean[rem] = acc; }
    }
    gridbar(slots, flags, ++ep);
    for (int idx=gtid; idx<MLEN*LATD; idx+=NTOT)
        stf(&Zf[idx], eps[idx]*__expf(0.5f*ldf(&LOGVf[idx])) + ldf(&MEANf[idx]));
    gridbar(slots, flags, ++ep);
    for (int idx=gtid; idx<MLEN*HD; idx+=NTOT){
        int i=idx/HD, j=idx%HD;
        const float* zr = Zf + (long)i*LATD;
        const float* wr = w_l2h + (long)j*LATD;
        float acc = b_l2h[j];
        for (int kk=0;kk<LATD;kk+=4){
            float4 wv = *(const float4*)(wr+kk);
            acc = fmaf(wv.x, ldf(zr+kk  ), acc); acc = fmaf(wv.y, ldf(zr+kk+1), acc);
            acc = fmaf(wv.z, ldf(zr+kk+2), acc); acc = fmaf(wv.w, ldf(zr+kk+3), acc);
        }
        stf(&LATf[idx], acc);
    }
    gridbar(slots, flags, ++ep);
    // Mf in j-major layout: Mf[j*MLEN + i] = dot(comb_w[j,600:], LAT[i,:])
    for (int idx=gtid; idx<MLEN*HD; idx+=NTOT){
        int j=idx/MLEN, i=idx%MLEN;
        const float* wr = comb_w + (long)j*1200 + HD;
        const float* lr = LATf + (long)i*HD;
        float acc = 0.f;
        for (int kk=0;kk<HD;kk+=4){
            float4 wv = *(const float4*)(wr+kk);
            acc = fmaf(wv.x, ldf(lr+kk  ), acc); acc = fmaf(wv.y, ldf(lr+kk+1), acc);
            acc = fmaf(wv.z, ldf(lr+kk+2), acc); acc = fmaf(wv.w, ldf(lr+kk+3), acc);
        }
        stf(&Mf[idx], acc);
    }
    gridbar(slots, flags, ++ep);

    // ---------------- DECODER ----------------
    {
        // one-time Mf -> LDS preload (read-only across all 50 steps)
        for (int idx=tid; idx<HD*MLEN; idx+=NTHR) mf_lds[idx] = ldf(&Mf[idx]);

        const float* wih = dir ? dec_wih_b : dec_wih_f;
        const float* bih = dir ? dec_bih_b : dec_bih_f;
        const float* whh = dir ? dec_whh_b : dec_whh_f;
        const float* bhh = dir ? dec_bhh_b : dec_bhh_f;
        float ur[10], uz[10], un[10];
        #pragma unroll
        for (int i=0;i<10;i++){
            int k2 = lane + 64*i;
            bool ok = k2 < HD;
            ur[i] = ok ? wih[(long)k*HD + k2] : 0.f;
            uz[i] = ok ? wih[(long)(HHD+k)*HD + k2] : 0.f;
            un[i] = ok ? wih[(long)(2*HHD+k)*HD + k2] : 0.f;
        }
        float vr[5], vz[5], vn[5];
        #pragma unroll
        for (int i=0;i<5;i++){
            int k2 = lane + 64*i;
            bool ok = k2 < HHD;
            vr[i] = ok ? whh[(long)k*HHD + k2] : 0.f;
            vz[i] = ok ? whh[(long)(HHD+k)*HHD + k2] : 0.f;
            vn[i] = ok ? whh[(long)(2*HHD+k)*HHD + k2] : 0.f;
        }
        const float bir = bih[k], biz = bih[HHD+k], bin_ = bih[2*HHD+k];
        const float bhr = bhh[k], bhz = bhh[HHD+k], bhn = bhh[2*HHD+k];

        for (int t=0; t<TTGT; t++){
            const float* hp = t ? (HSs + (long)(t-1)*ESTR) : (ENCf + (long)(TIN-1)*ESTR);
            for (int j=tid; j<HD; j+=NTHR) h_lds[j] = ldf(hp+j);
            // hoisted CPRE seeds (overlap MALL latency with attention+softmax)
            float cp0 = (tid < HD) ? ldf(&CPREf[(long)t*HD + tid]) : 0.f;
            float cp1 = (tid + NTHR < HD) ? ldf(&CPREf[(long)t*HD + tid + NTHR]) : 0.f;
            __syncthreads();
            // attention scores (replicated per block)
            for (int a=wid; a<MLEN; a+=8){
                const float* arow = attn_w + (long)a*1200 + HD;
                float acc = 0.f;
                #pragma unroll
                for (int i=0;i<10;i++){
                    int kk = lane + 64*i;
                    if (kk < HD) acc = fmaf(arow[kk], h_lds[kk], acc);
                }
                #pragma unroll
                for (int off=32;off;off>>=1) acc += __shfl_xor(acc,off);
                if (lane==0) s_lds[a] = acc + ldf(&APREf[t*MLEN + a]);
            }
            __syncthreads();
            // softmax — R1-exact serial form (one thread)
            if (tid==0){
                float m = -1e30f;
                for (int a=0;a<MLEN;a++) m = fmaxf(m, s_lds[a]);
                float sum = 0.f;
                for (int a=0;a<MLEN;a++){ float e = __expf(s_lds[a]-m); aw_lds[a]=e; sum+=e; }
                float inv = 1.f/sum;
                for (int a=0;a<MLEN;a++) aw_lds[a] *= inv;
            }
            __syncthreads();
            // o = relu(CPRE + M^T aw) — Mf from LDS, i ascending (identical order)
            for (int j=tid; j<HD; j+=NTHR){
                float acc = (j==tid) ? cp0 : cp1;
                const float* mr = &mf_lds[j*MLEN];
                #pragma unroll
                for (int i=0;i<MLEN;i++) acc = fmaf(mr[i], aw_lds[i], acc);
                o_lds[j] = fmaxf(acc, 0.f);
            }
            __syncthreads();
            // GRU cells
            float ar=0,az=0,an=0, hr=0,hz=0,hn=0;
            #pragma unroll
            for (int i=0;i<10;i++){
                float ov = o_lds[lane + 64*i];
                ar = fmaf(ur[i], ov, ar);
                az = fmaf(uz[i], ov, az);
                an = fmaf(un[i], ov, an);
            }
            #pragma unroll
            for (int i=0;i<5;i++){
                float hv = h_lds[dir*HHD + lane + 64*i];
                hr = fmaf(vr[i], hv, hr);
                hz = fmaf(vz[i], hv, hz);
                hn = fmaf(vn[i], hv, hn);
            }
            redu6(ar,az,an,hr,hz,hn);
            if (lane==0){
                float r = sigf(ar + bir + hr + bhr);
                float zg = sigf(az + biz + hz + bhz);
                float n = tanhf(an + bin_ + r*(hn + bhn));
                float hnew = (1.f-zg)*n + zg*h_lds[dir*HHD + k];
                stf(&HSs[(long)t*ESTR + dir*HHD + k], hnew);
                HSv[(long)t*HD + dir*HHD + k] = hnew;   // for k_vocab (next kernel)
            }
            if (t < TTGT-1) gridbar(slots, flags, ++ep);
        }
    }
}

// ---------------- vocab projection: bf16 MFMA, fused f32->bf16 ----------------
__device__ __forceinline__ s16x8 pack8(const float* __restrict__ p){
    s16x8 r;
    #pragma unroll
    for (int i=0;i<8;i++){
        unsigned u = __float_as_uint(p[i]);
        r[i] = (short)((u + 0x7fffu + ((u>>16)&1u)) >> 16);
    }
    return r;
}

__global__ void __launch_bounds__(256) k_vocab(const float* __restrict__ out_w,
        const float* __restrict__ out_b, const float* __restrict__ HS,
        float* __restrict__ logits){
    int lane = threadIdx.x & 63, wid = threadIdx.x >> 6;
    int vbase = blockIdx.x*64 + wid*16;
    int arow  = vbase + (lane & 15);
    int kg    = (lane >> 4) * 8;
    bool aok  = arow < VSZ;
    const float* ap = out_w + (long)(aok ? arow : 0) * HD;
    int t0 = lane & 15;
    f32x4 acc0 = {0,0,0,0}, acc1 = acc0, acc2 = acc0, acc3 = acc0;
    const s16x8 zf = (s16x8)0;

    for (int ks=0; ks<19; ks++){
        int kb = ks*32 + kg;
        bool kok = kb < HD;
        s16x8 a = (aok && kok) ? pack8(ap + kb) : zf;
        s16x8 b0 = kok              ? pack8(HS + (long)(t0     )*HD + kb) : zf;
        s16x8 b1 = kok              ? pack8(HS + (long)(t0 + 16)*HD + kb) : zf;
        s16x8 b2 = kok              ? pack8(HS + (long)(t0 + 32)*HD + kb) : zf;
        s16x8 b3 = (kok && t0 < 2)  ? pack8(HS + (long)(t0 + 48)*HD + kb) : zf;
        acc0 = __builtin_amdgcn_mfma_f32_16x16x32_bf16(a, b0, acc0, 0,0,0);
        acc1 = __builtin_amdgcn_mfma_f32_16x16x32_bf16(a, b1, acc1, 0,0,0);
        acc2 = __builtin_amdgcn_mfma_f32_16x16x32_bf16(a, b2, acc2, 0,0,0);
        acc3 = __builtin_amdgcn_mfma_f32_16x16x32_bf16(a, b3, acc3, 0,0,0);
    }

    int vst = vbase + (lane>>4)*4;
    float bb[4];
    #pragma unroll
    for (int r=0;r<4;r++) bb[r] = (vst+r < VSZ) ? out_b[vst+r] : 0.f;
    #pragma unroll
    for (int f=0; f<4; f++){
        int t = t0 + 16*f;
        if (t >= TTGT) continue;
        const f32x4 acc = f==0?acc0 : f==1?acc1 : f==2?acc2 : acc3;
        float* rowp = logits + (long)t*VSZ;
        #pragma unroll
        for (int r=0;r<4;r++){
            int v = vst + r;
            if (v < VSZ) rowp[v] = acc[r] + bb[r];
        }
    }
}

// in-place log-softmax per step row
__global__ void __launch_bounds__(1024) k_lsm(float* __restrict__ logits){
    __shared__ float red[16];
    __shared__ float sm, sl;
    long t = blockIdx.x;
    float* row = logits + t*VSZ;
    int tid = threadIdx.x, lane = tid&63, w = tid>>6;
    float m = -1e30f;
    for (int v=tid; v<VSZ; v+=1024) m = fmaxf(m, row[v]);
    #pragma unroll
    for (int off=32;off;off>>=1) m = fmaxf(m, __shfl_xor(m,off));
    if (lane==0) red[w] = m;
    __syncthreads();
    if (tid==0){ float mm=red[0]; for (int i=1;i<16;i++) mm=fmaxf(mm,red[i]); sm=mm; }
    __syncthreads();
    float mx = sm;
    float s = 0.f;
    for (int v=tid; v<VSZ; v+=1024) s += __expf(row[v]-mx);
    #pragma unroll
    for (int off=32;off;off>>=1) s += __shfl_xor(s,off);
    __syncthreads();
    if (lane==0) red[w] = s;
    __syncthreads();
    if (tid==0){ float ss=0.f; for (int i=0;i<16;i++) ss+=red[i]; sl = logf(ss); }
    __syncthreads();
    float lg = sl;
    for (int v=tid; v<VSZ; v+=1024) row[v] = row[v] - mx - lg;
}

extern "C" void kernel_launch(void* const* d_in, const int* in_sizes, int n_in,
                              void* d_out, int out_size, void* d_ws, size_t ws_size,
                              hipStream_t stream) {
    const float* emb_enc   = (const float*)d_in[0];
    const float* emb_dec   = (const float*)d_in[1];
    const float* enc_wih_f = (const float*)d_in[2];
    const float* enc_whh_f = (const float*)d_in[3];
    const float* enc_bih_f = (const float*)d_in[4];
    const float* enc_bhh_f = (const float*)d_in[5];
    const float* enc_wih_b = (const float*)d_in[6];
    const float* enc_whh_b = (const float*)d_in[7];
    const float* enc_bih_b = (const float*)d_in[8];
    const float* enc_bhh_b = (const float*)d_in[9];
    const float* dec_wih_f = (const float*)d_in[10];
    const float* dec_whh_f = (const float*)d_in[11];
    const float* dec_bih_f = (const float*)d_in[12];
    const float* dec_bhh_f = (const float*)d_in[13];
    const float* dec_wih_b = (const float*)d_in[14];
    const float* dec_whh_b = (const float*)d_in[15];
    const float* dec_bih_b = (const float*)d_in[16];
    const float* dec_bhh_b = (const float*)d_in[17];
    const float* w_mean    = (const float*)d_in[18];
    const float* b_mean    = (const float*)d_in[19];
    const float* w_logv    = (const float*)d_in[20];
    const float* b_logv    = (const float*)d_in[21];
    const float* w_l2h     = (const float*)d_in[22];
    const float* b_l2h     = (const float*)d_in[23];
    const float* attn_w    = (const float*)d_in[24];
    const float* attn_b    = (const float*)d_in[25];
    const float* comb_w    = (const float*)d_in[26];
    const float* comb_b    = (const float*)d_in[27];
    const float* out_w     = (const float*)d_in[28];
    const float* out_b     = (const float*)d_in[29];
    const float* eps       = (const float*)d_in[30];
    const int*   in_toks   = (const int*)d_in[31];
    const int*   tgt_toks  = (const int*)d_in[32];

    float* ws = (float*)d_ws;                  // all offsets 128B-aligned
    float* GIf   = ws;                         // 48*1800 = 86400
    float* ENCf  = ws + 86400;                 // 50*640  = 32000
    float* MEANf = ws + 118400;                // 5024
    float* LOGVf = ws + 123424;                // 5024
    float* Zf    = ws + 128448;                // 5024
    float* LATf  = ws + 133472;                // 30016
    float* Mf    = ws + 163488;                // 30016 ([j][i], stride 50)
    float* APREf = ws + 193504;                // 2528
    float* CPREf = ws + 196032;                // 30016
    float* HSs   = ws + 226048;                // 50*640 = 32000 (padded state)
    float* HSv   = ws + 258048;                // 50*600 = 30016 (for k_vocab)
    int*   slots = (int*)(ws + 288064);        // 75*32 ints
    int*   flags = (int*)(ws + 290464);        // 75*32 ints

    float* dec_out  = (float*)d_out;
    float* out_mean = dec_out + 2500000;
    float* out_logv = dec_out + 2505000;

    k_init<<<(2*NBLK*SLOT_STRIDE + 255)/256, 256, 0, stream>>>((int*)(ws + 288064));

    k_seq<<<NBLK, NTHR, 0, stream>>>(
        emb_enc, emb_dec,
        enc_wih_f, enc_whh_f, enc_bih_f, enc_bhh_f,
        enc_wih_b, enc_whh_b, enc_bih_b, enc_bhh_b,
        dec_wih_f, dec_whh_f, dec_bih_f, dec_bhh_f,
        dec_wih_b, dec_whh_b, dec_bih_b, dec_bhh_b,
        w_mean, b_mean, w_logv, b_logv, w_l2h, b_l2h,
        attn_w, attn_b, comb_w, comb_b,
        eps, in_toks, tgt_toks,
        GIf, ENCf, MEANf, LOGVf, Zf, LATf, Mf, APREf, CPREf, HSs, HSv,
        out_mean, out_logv, slots, flags);

    k_vocab<<<(VSZ + 63)/64, 256, 0, stream>>>(out_w, out_b, HSv, dec_out);
    k_lsm<<<TTGT, 1024, 0, stream>>>(dec_out);
}

// Round 6
// 922.458 us; speedup vs baseline: 2.3058x; 1.1960x over previous
//
#include <hip/hip_runtime.h>
#include <math.h>

#define VSZ 50000
#define HD 600
#define HHD 300
#define LATD 100
#define MLEN 50
#define TIN 48
#define TTGT 50
#define NBLK 75
#define NTHR 512
#define NTOT (NBLK*NTHR)
#define ESTR 640              // padded row stride (2560B = 40 cache lines)
#define SLOT_STRIDE 32        // ints; 128B between slots

typedef __attribute__((ext_vector_type(4))) float f32x4;
typedef __attribute__((ext_vector_type(8))) short s16x8;

__device__ __forceinline__ float sigf(float x){ return 1.0f/(1.0f+__expf(-x)); }

// agent-scope (coherent-point) store: write-through past non-coherent L2s.
// Reads use PLAIN cached loads: every exchanged line is write-once then
// read-later (first read misses L2 -> fetched from memory-side MALL = fresh;
// any stale hit across graph replays holds bit-identical values).
__device__ __forceinline__ void stf(float* p, float v){
    __hip_atomic_store((unsigned int*)p, __float_as_uint(v),
                       __ATOMIC_RELAXED, __HIP_MEMORY_SCOPE_AGENT);
}
__device__ __forceinline__ int ldslot(const int* p){
    return __hip_atomic_load(p, __ATOMIC_RELAXED, __HIP_MEMORY_SCOPE_AGENT);
}
__device__ __forceinline__ void stslot(int* p, int v){
    __hip_atomic_store(p, v, __ATOMIC_RELAXED, __HIP_MEMORY_SCOPE_AGENT);
}

__device__ __forceinline__ void redu3(float&a,float&b,float&c){
    #pragma unroll
    for(int off=32;off;off>>=1){
        a+=__shfl_xor(a,off); b+=__shfl_xor(b,off); c+=__shfl_xor(c,off);
    }
}
__device__ __forceinline__ void redu6(float&a,float&b,float&c,float&d,float&e,float&f){
    #pragma unroll
    for(int off=32;off;off>>=1){
        a+=__shfl_xor(a,off); b+=__shfl_xor(b,off); c+=__shfl_xor(c,off);
        d+=__shfl_xor(d,off); e+=__shfl_xor(e,off); f+=__shfl_xor(f,off);
    }
}

// Two-level leader barrier (1 writer + 1 poller per cache line)
__device__ __forceinline__ void gridbar(int* slots, int* flags, int e){
    asm volatile("s_waitcnt vmcnt(0)" ::: "memory");
    __syncthreads();
    const int tid = threadIdx.x;
    if (tid == 0) stslot(&slots[blockIdx.x*SLOT_STRIDE], e);
    if (blockIdx.x == 0){
        if (tid < NBLK){
            while (ldslot(&slots[tid*SLOT_STRIDE]) < e)
                __builtin_amdgcn_s_sleep(1);
        }
        __syncthreads();
        if (tid < NBLK) stslot(&flags[tid*SLOT_STRIDE], e);
    } else {
        if (tid == 0){
            while (ldslot(&flags[blockIdx.x*SLOT_STRIDE]) < e)
                __builtin_amdgcn_s_sleep(1);
        }
    }
    __syncthreads();
}

__global__ void k_init(int* sync_mem){
    int i = blockIdx.x*blockDim.x + threadIdx.x;
    if (i < 2*NBLK*SLOT_STRIDE) sync_mem[i] = 0;
}

__global__ void __launch_bounds__(NTHR) k_seq(
    const float* __restrict__ emb_enc, const float* __restrict__ emb_dec,
    const float* __restrict__ enc_wih_f, const float* __restrict__ enc_whh_f,
    const float* __restrict__ enc_bih_f, const float* __restrict__ enc_bhh_f,
    const float* __restrict__ enc_wih_b, const float* __restrict__ enc_whh_b,
    const float* __restrict__ enc_bih_b, const float* __restrict__ enc_bhh_b,
    const float* __restrict__ dec_wih_f, const float* __restrict__ dec_whh_f,
    const float* __restrict__ dec_bih_f, const float* __restrict__ dec_bhh_f,
    const float* __restrict__ dec_wih_b, const float* __restrict__ dec_whh_b,
    const float* __restrict__ dec_bih_b, const float* __restrict__ dec_bhh_b,
    const float* __restrict__ w_mean, const float* __restrict__ b_mean,
    const float* __restrict__ w_logv, const float* __restrict__ b_logv,
    const float* __restrict__ w_l2h, const float* __restrict__ b_l2h,
    const float* __restrict__ attn_w, const float* __restrict__ attn_b,
    const float* __restrict__ comb_w, const float* __restrict__ comb_b,
    const float* __restrict__ eps, const int* __restrict__ in_toks,
    const int* __restrict__ tgt_toks,
    float* __restrict__ GIf, float* __restrict__ ENCf,
    float* __restrict__ MEANf, float* __restrict__ LOGVf,
    float* __restrict__ Zf, float* __restrict__ LATf, float* __restrict__ Mf,
    float* __restrict__ APREf, float* __restrict__ CPREf,
    float* __restrict__ HSs, float* __restrict__ HSv,
    float* __restrict__ out_mean, float* __restrict__ out_logv,
    int* slots, int* flags){

    __shared__ float h_lds[ESTR];
    __shared__ float o_lds[ESTR];
    __shared__ float s_lds[64];
    __shared__ float aw_lds[64];
    __shared__ float mf_lds[HD*MLEN];   // 120 KB: Mf[j][i], resident all decoder steps

    const int tid  = threadIdx.x;
    const int lane = tid & 63;
    const int wid  = tid >> 6;
    const int gtid = blockIdx.x*NTHR + tid;
    const int gw   = blockIdx.x*8 + wid;      // 0..599
    const int dir  = gw / HHD;
    const int k    = gw % HHD;
    int ep = 0;

    if (tid < ESTR-HD){ h_lds[HD+tid]=0.f; o_lds[HD+tid]=0.f; }

    // ---------------- PRE PHASE ----------------
    if (gtid < (MLEN-TIN)*ESTR) stf(&ENCf[TIN*ESTR + gtid], 0.f);
    // GI: R1-exact bias-seeded single fmaf chain
    for (int idx=gtid; idx<TIN*1800; idx+=NTOT){
        int t=idx/1800, r=idx%1800, d=r/900, j=r%900;
        const float* w  = d ? enc_wih_b : enc_wih_f;
        const float* bi = d ? enc_bih_b : enc_bih_f;
        const float* x  = emb_enc + (long)in_toks[t]*HD;
        const float* wr = w + (long)j*HD;
        float acc = bi[j];
        for (int kk=0;kk<HD;kk+=4){
            float4 wv = *(const float4*)(wr+kk);
            float4 xv = *(const float4*)(x+kk);
            acc = fmaf(wv.x,xv.x,acc); acc = fmaf(wv.y,xv.y,acc);
            acc = fmaf(wv.z,xv.z,acc); acc = fmaf(wv.w,xv.w,acc);
        }
        stf(&GIf[idx], acc);
    }
    for (int idx=gtid; idx<TTGT*MLEN; idx+=NTOT){
        int t=idx/MLEN, a=idx%MLEN;
        int tok = t ? tgt_toks[t-1] : 1;
        const float* x  = emb_dec + (long)tok*HD;
        const float* wr = attn_w + (long)a*1200;
        float acc = attn_b[a];
        for (int kk=0;kk<HD;kk+=4){
            float4 wv = *(const float4*)(wr+kk);
            float4 xv = *(const float4*)(x+kk);
            acc = fmaf(wv.x,xv.x,acc); acc = fmaf(wv.y,xv.y,acc);
            acc = fmaf(wv.z,xv.z,acc); acc = fmaf(wv.w,xv.w,acc);
        }
        stf(&APREf[idx], acc);
    }
    for (int idx=gtid; idx<TTGT*HD; idx+=NTOT){
        int t=idx/HD, j=idx%HD;
        int tok = t ? tgt_toks[t-1] : 1;
        const float* x  = emb_dec + (long)tok*HD;
        const float* wr = comb_w + (long)j*1200;
        float acc = comb_b[j];
        for (int kk=0;kk<HD;kk+=4){
            float4 wv = *(const float4*)(wr+kk);
            float4 xv = *(const float4*)(x+kk);
            acc = fmaf(wv.x,xv.x,acc); acc = fmaf(wv.y,xv.y,acc);
            acc = fmaf(wv.z,xv.z,acc); acc = fmaf(wv.w,xv.w,acc);
        }
        stf(&CPREf[idx], acc);
    }
    gridbar(slots, flags, ++ep);

    // ---------------- ENCODER ----------------
    {
        const float* whh = dir ? enc_whh_b : enc_whh_f;
        const float* bhh = dir ? enc_bhh_b : enc_bhh_f;
        float wr_[5], wz_[5], wn_[5];
        #pragma unroll
        for (int i=0;i<5;i++){
            int k2 = lane + 64*i;
            bool ok = k2 < HHD;
            wr_[i] = ok ? whh[(long)k*HHD + k2] : 0.f;
            wz_[i] = ok ? whh[(long)(HHD+k)*HHD + k2] : 0.f;
            wn_[i] = ok ? whh[(long)(2*HHD+k)*HHD + k2] : 0.f;
        }
        const float bhr = bhh[k], bhz = bhh[HHD+k], bhn = bhh[2*HHD+k];
        float gr=0, gz=0, gn=0;
        if (lane < TIN){
            const float* g = GIf + (long)lane*1800 + dir*900;   // cached reads
            gr = g[k]; gz = g[HHD+k]; gn = g[2*HHD+k];
        }
        for (int t=0; t<TIN; t++){
            if (t){
                if (tid < HD/4)
                    *(float4*)&h_lds[4*tid] = *(const float4*)&ENCf[(long)(t-1)*ESTR + 4*tid];
            } else {
                if (tid < HD) h_lds[tid] = 0.f;
            }
            __syncthreads();
            float sr=0, sz=0, sn=0;
            #pragma unroll
            for (int i=0;i<5;i++){
                float hv = h_lds[dir*HHD + lane + 64*i];
                sr = fmaf(wr_[i], hv, sr);
                sz = fmaf(wz_[i], hv, sz);
                sn = fmaf(wn_[i], hv, sn);
            }
            redu3(sr, sz, sn);
            float grt=__shfl(gr,t), gzt=__shfl(gz,t), gnt=__shfl(gn,t);
            if (lane==0){
                float r = sigf(grt + sr + bhr);
                float z = sigf(gzt + sz + bhz);
                float n = tanhf(gnt + r*(sn + bhn));
                float hp = h_lds[dir*HHD + k];
                stf(&ENCf[(long)t*ESTR + dir*HHD + k], (1.f-z)*n + z*hp);
            }
            gridbar(slots, flags, ++ep);
        }
    }

    // ---------------- LATENT ----------------
    for (int idx=gtid; idx<2*MLEN*LATD; idx+=NTOT){
        int which=idx/(MLEN*LATD), rem=idx%(MLEN*LATD), i=rem/LATD, l=rem%LATD;
        const float* W = which ? w_logv : w_mean;
        const float* B = which ? b_logv : b_mean;
        const float* e = ENCf + (long)i*ESTR;
        const float* wr = W + (long)l*HD;
        float acc = B[l];
        for (int kk=0;kk<HD;kk+=4){
            float4 wv = *(const float4*)(wr+kk);
            float4 ev = *(const float4*)(e+kk);
            acc = fmaf(wv.x,ev.x,acc); acc = fmaf(wv.y,ev.y,acc);
            acc = fmaf(wv.z,ev.z,acc); acc = fmaf(wv.w,ev.w,acc);
        }
        if (which){ stf(&LOGVf[rem], acc); out_logv[rem] = acc; }
        else      { stf(&MEANf[rem], acc); out_mean[rem] = acc; }
    }
    gridbar(slots, flags, ++ep);
    for (int idx=gtid; idx<MLEN*LATD; idx+=NTOT)
        stf(&Zf[idx], eps[idx]*__expf(0.5f*LOGVf[idx]) + MEANf[idx]);
    gridbar(slots, flags, ++ep);
    for (int idx=gtid; idx<MLEN*HD; idx+=NTOT){
        int i=idx/HD, j=idx%HD;
        const float* zr = Zf + (long)i*LATD;
        const float* wr = w_l2h + (long)j*LATD;
        float acc = b_l2h[j];
        for (int kk=0;kk<LATD;kk+=4){
            float4 wv = *(const float4*)(wr+kk);
            float4 zv = *(const float4*)(zr+kk);
            acc = fmaf(wv.x,zv.x,acc); acc = fmaf(wv.y,zv.y,acc);
            acc = fmaf(wv.z,zv.z,acc); acc = fmaf(wv.w,zv.w,acc);
        }
        stf(&LATf[idx], acc);
    }
    gridbar(slots, flags, ++ep);
    // Mf in j-major layout: Mf[j*MLEN + i] = dot(comb_w[j,600:], LAT[i,:])
    for (int idx=gtid; idx<MLEN*HD; idx+=NTOT){
        int j=idx/MLEN, i=idx%MLEN;
        const float* wr = comb_w + (long)j*1200 + HD;
        const float* lr = LATf + (long)i*HD;
        float acc = 0.f;
        for (int kk=0;kk<HD;kk+=4){
            float4 wv = *(const float4*)(wr+kk);
            float4 lv = *(const float4*)(lr+kk);
            acc = fmaf(wv.x,lv.x,acc); acc = fmaf(wv.y,lv.y,acc);
            acc = fmaf(wv.z,lv.z,acc); acc = fmaf(wv.w,lv.w,acc);
        }
        stf(&Mf[idx], acc);
    }
    gridbar(slots, flags, ++ep);

    // ---------------- DECODER ----------------
    {
        // one-time Mf -> LDS preload (cached float4 reads)
        for (int idx=tid; idx<HD*MLEN/4; idx+=NTHR)
            *(float4*)&mf_lds[4*idx] = *(const float4*)&Mf[4*idx];

        const float* wih = dir ? dec_wih_b : dec_wih_f;
        const float* bih = dir ? dec_bih_b : dec_bih_f;
        const float* whh = dir ? dec_whh_b : dec_whh_f;
        const float* bhh = dir ? dec_bhh_b : dec_bhh_f;
        float ur[10], uz[10], un[10];
        #pragma unroll
        for (int i=0;i<10;i++){
            int k2 = lane + 64*i;
            bool ok = k2 < HD;
            ur[i] = ok ? wih[(long)k*HD + k2] : 0.f;
            uz[i] = ok ? wih[(long)(HHD+k)*HD + k2] : 0.f;
            un[i] = ok ? wih[(long)(2*HHD+k)*HD + k2] : 0.f;
        }
        float vr[5], vz[5], vn[5];
        #pragma unroll
        for (int i=0;i<5;i++){
            int k2 = lane + 64*i;
            bool ok = k2 < HHD;
            vr[i] = ok ? whh[(long)k*HHD + k2] : 0.f;
            vz[i] = ok ? whh[(long)(HHD+k)*HHD + k2] : 0.f;
            vn[i] = ok ? whh[(long)(2*HHD+k)*HHD + k2] : 0.f;
        }
        const float bir = bih[k], biz = bih[HHD+k], bin_ = bih[2*HHD+k];
        const float bhr = bhh[k], bhz = bhh[HHD+k], bhn = bhh[2*HHD+k];

        for (int t=0; t<TTGT; t++){
            const float* hp = t ? (HSs + (long)(t-1)*ESTR) : (ENCf + (long)(TIN-1)*ESTR);
            if (tid < HD/4)
                *(float4*)&h_lds[4*tid] = *(const float4*)&hp[4*tid];
            // hoisted CPRE seeds (cached)
            float cp0 = (tid < HD) ? CPREf[(long)t*HD + tid] : 0.f;
            float cp1 = (tid + NTHR < HD) ? CPREf[(long)t*HD + tid + NTHR] : 0.f;
            __syncthreads();
            // attention scores (replicated per block)
            for (int a=wid; a<MLEN; a+=8){
                const float* arow = attn_w + (long)a*1200 + HD;
                float acc = 0.f;
                #pragma unroll
                for (int i=0;i<10;i++){
                    int kk = lane + 64*i;
                    if (kk < HD) acc = fmaf(arow[kk], h_lds[kk], acc);
                }
                #pragma unroll
                for (int off=32;off;off>>=1) acc += __shfl_xor(acc,off);
                if (lane==0) s_lds[a] = acc + APREf[t*MLEN + a];
            }
            __syncthreads();
            // softmax — R1-exact serial form (one thread)
            if (tid==0){
                float m = -1e30f;
                for (int a=0;a<MLEN;a++) m = fmaxf(m, s_lds[a]);
                float sum = 0.f;
                for (int a=0;a<MLEN;a++){ float e = __expf(s_lds[a]-m); aw_lds[a]=e; sum+=e; }
                float inv = 1.f/sum;
                for (int a=0;a<MLEN;a++) aw_lds[a] *= inv;
            }
            __syncthreads();
            // o = relu(CPRE + M^T aw) — Mf from LDS, i ascending (identical order)
            for (int j=tid; j<HD; j+=NTHR){
                float acc = (j==tid) ? cp0 : cp1;
                const float* mr = &mf_lds[j*MLEN];
                #pragma unroll
                for (int i=0;i<MLEN;i++) acc = fmaf(mr[i], aw_lds[i], acc);
                o_lds[j] = fmaxf(acc, 0.f);
            }
            __syncthreads();
            // GRU cells
            float ar=0,az=0,an=0, hr=0,hz=0,hn=0;
            #pragma unroll
            for (int i=0;i<10;i++){
                float ov = o_lds[lane + 64*i];
                ar = fmaf(ur[i], ov, ar);
                az = fmaf(uz[i], ov, az);
                an = fmaf(un[i], ov, an);
            }
            #pragma unroll
            for (int i=0;i<5;i++){
                float hv = h_lds[dir*HHD + lane + 64*i];
                hr = fmaf(vr[i], hv, hr);
                hz = fmaf(vz[i], hv, hz);
                hn = fmaf(vn[i], hv, hn);
            }
            redu6(ar,az,an,hr,hz,hn);
            if (lane==0){
                float r = sigf(ar + bir + hr + bhr);
                float zg = sigf(az + biz + hz + bhz);
                float n = tanhf(an + bin_ + r*(hn + bhn));
                float hnew = (1.f-zg)*n + zg*h_lds[dir*HHD + k];
                stf(&HSs[(long)t*ESTR + dir*HHD + k], hnew);
                HSv[(long)t*HD + dir*HHD + k] = hnew;   // plain store for k_vocab
            }
            if (t < TTGT-1) gridbar(slots, flags, ++ep);
        }
    }
}

// ---------------- vocab projection: bf16 MFMA, fused f32->bf16 ----------------
__device__ __forceinline__ s16x8 pack8(const float* __restrict__ p){
    s16x8 r;
    #pragma unroll
    for (int i=0;i<8;i++){
        unsigned u = __float_as_uint(p[i]);
        r[i] = (short)((u + 0x7fffu + ((u>>16)&1u)) >> 16);
    }
    return r;
}

__global__ void __launch_bounds__(256) k_vocab(const float* __restrict__ out_w,
        const float* __restrict__ out_b, const float* __restrict__ HS,
        float* __restrict__ logits){
    int lane = threadIdx.x & 63, wid = threadIdx.x >> 6;
    int vbase = blockIdx.x*64 + wid*16;
    int arow  = vbase + (lane & 15);
    int kg    = (lane >> 4) * 8;
    bool aok  = arow < VSZ;
    const float* ap = out_w + (long)(aok ? arow : 0) * HD;
    int t0 = lane & 15;
    f32x4 acc0 = {0,0,0,0}, acc1 = acc0, acc2 = acc0, acc3 = acc0;
    const s16x8 zf = (s16x8)0;

    for (int ks=0; ks<19; ks++){
        int kb = ks*32 + kg;
        bool kok = kb < HD;
        s16x8 a = (aok && kok) ? pack8(ap + kb) : zf;
        s16x8 b0 = kok              ? pack8(HS + (long)(t0     )*HD + kb) : zf;
        s16x8 b1 = kok              ? pack8(HS + (long)(t0 + 16)*HD + kb) : zf;
        s16x8 b2 = kok              ? pack8(HS + (long)(t0 + 32)*HD + kb) : zf;
        s16x8 b3 = (kok && t0 < 2)  ? pack8(HS + (long)(t0 + 48)*HD + kb) : zf;
        acc0 = __builtin_amdgcn_mfma_f32_16x16x32_bf16(a, b0, acc0, 0,0,0);
        acc1 = __builtin_amdgcn_mfma_f32_16x16x32_bf16(a, b1, acc1, 0,0,0);
        acc2 = __builtin_amdgcn_mfma_f32_16x16x32_bf16(a, b2, acc2, 0,0,0);
        acc3 = __builtin_amdgcn_mfma_f32_16x16x32_bf16(a, b3, acc3, 0,0,0);
    }

    int vst = vbase + (lane>>4)*4;
    float bb[4];
    #pragma unroll
    for (int r=0;r<4;r++) bb[r] = (vst+r < VSZ) ? out_b[vst+r] : 0.f;
    #pragma unroll
    for (int f=0; f<4; f++){
        int t = t0 + 16*f;
        if (t >= TTGT) continue;
        const f32x4 acc = f==0?acc0 : f==1?acc1 : f==2?acc2 : acc3;
        float* rowp = logits + (long)t*VSZ;
        #pragma unroll
        for (int r=0;r<4;r++){
            int v = vst + r;
            if (v < VSZ) rowp[v] = acc[r] + bb[r];
        }
    }
}

// in-place log-softmax per step row
__global__ void __launch_bounds__(1024) k_lsm(float* __restrict__ logits){
    __shared__ float red[16];
    __shared__ float sm, sl;
    long t = blockIdx.x;
    float* row = logits + t*VSZ;
    int tid = threadIdx.x, lane = tid&63, w = tid>>6;
    float m = -1e30f;
    for (int v=tid; v<VSZ; v+=1024) m = fmaxf(m, row[v]);
    #pragma unroll
    for (int off=32;off;off>>=1) m = fmaxf(m, __shfl_xor(m,off));
    if (lane==0) red[w] = m;
    __syncthreads();
    if (tid==0){ float mm=red[0]; for (int i=1;i<16;i++) mm=fmaxf(mm,red[i]); sm=mm; }
    __syncthreads();
    float mx = sm;
    float s = 0.f;
    for (int v=tid; v<VSZ; v+=1024) s += __expf(row[v]-mx);
    #pragma unroll
    for (int off=32;off;off>>=1) s += __shfl_xor(s,off);
    __syncthreads();
    if (lane==0) red[w] = s;
    __syncthreads();
    if (tid==0){ float ss=0.f; for (int i=0;i<16;i++) ss+=red[i]; sl = logf(ss); }
    __syncthreads();
    float lg = sl;
    for (int v=tid; v<VSZ; v+=1024) row[v] = row[v] - mx - lg;
}

extern "C" void kernel_launch(void* const* d_in, const int* in_sizes, int n_in,
                              void* d_out, int out_size, void* d_ws, size_t ws_size,
                              hipStream_t stream) {
    const float* emb_enc   = (const float*)d_in[0];
    const float* emb_dec   = (const float*)d_in[1];
    const float* enc_wih_f = (const float*)d_in[2];
    const float* enc_whh_f = (const float*)d_in[3];
    const float* enc_bih_f = (const float*)d_in[4];
    const float* enc_bhh_f = (const float*)d_in[5];
    const float* enc_wih_b = (const float*)d_in[6];
    const float* enc_whh_b = (const float*)d_in[7];
    const float* enc_bih_b = (const float*)d_in[8];
    const float* enc_bhh_b = (const float*)d_in[9];
    const float* dec_wih_f = (const float*)d_in[10];
    const float* dec_whh_f = (const float*)d_in[11];
    const float* dec_bih_f = (const float*)d_in[12];
    const float* dec_bhh_f = (const float*)d_in[13];
    const float* dec_wih_b = (const float*)d_in[14];
    const float* dec_whh_b = (const float*)d_in[15];
    const float* dec_bih_b = (const float*)d_in[16];
    const float* dec_bhh_b = (const float*)d_in[17];
    const float* w_mean    = (const float*)d_in[18];
    const float* b_mean    = (const float*)d_in[19];
    const float* w_logv    = (const float*)d_in[20];
    const float* b_logv    = (const float*)d_in[21];
    const float* w_l2h     = (const float*)d_in[22];
    const float* b_l2h     = (const float*)d_in[23];
    const float* attn_w    = (const float*)d_in[24];
    const float* attn_b    = (const float*)d_in[25];
    const float* comb_w    = (const float*)d_in[26];
    const float* comb_b    = (const float*)d_in[27];
    const float* out_w     = (const float*)d_in[28];
    const float* out_b     = (const float*)d_in[29];
    const float* eps       = (const float*)d_in[30];
    const int*   in_toks   = (const int*)d_in[31];
    const int*   tgt_toks  = (const int*)d_in[32];

    float* ws = (float*)d_ws;                  // all offsets 128B-aligned
    float* GIf   = ws;                         // 48*1800 = 86400
    float* ENCf  = ws + 86400;                 // 50*640  = 32000
    float* MEANf = ws + 118400;                // 5024
    float* LOGVf = ws + 123424;                // 5024
    float* Zf    = ws + 128448;                // 5024
    float* LATf  = ws + 133472;                // 30016
    float* Mf    = ws + 163488;                // 30016 ([j][i], stride 50)
    float* APREf = ws + 193504;                // 2528
    float* CPREf = ws + 196032;                // 30016
    float* HSs   = ws + 226048;                // 50*640 = 32000 (padded state)
    float* HSv   = ws + 258048;                // 50*600 = 30016 (for k_vocab)
    int*   slots = (int*)(ws + 288064);        // 75*32 ints
    int*   flags = (int*)(ws + 290464);        // 75*32 ints

    float* dec_out  = (float*)d_out;
    float* out_mean = dec_out + 2500000;
    float* out_logv = dec_out + 2505000;

    k_init<<<(2*NBLK*SLOT_STRIDE + 255)/256, 256, 0, stream>>>((int*)(ws + 288064));

    k_seq<<<NBLK, NTHR, 0, stream>>>(
        emb_enc, emb_dec,
        enc_wih_f, enc_whh_f, enc_bih_f, enc_bhh_f,
        enc_wih_b, enc_whh_b, enc_bih_b, enc_bhh_b,
        dec_wih_f, dec_whh_f, dec_bih_f, dec_bhh_f,
        dec_wih_b, dec_whh_b, dec_bih_b, dec_bhh_b,
        w_mean, b_mean, w_logv, b_logv, w_l2h, b_l2h,
        attn_w, attn_b, comb_w, comb_b,
        eps, in_toks, tgt_toks,
        GIf, ENCf, MEANf, LOGVf, Zf, LATf, Mf, APREf, CPREf, HSs, HSv,
        out_mean, out_logv, slots, flags);

    k_vocab<<<(VSZ + 63)/64, 256, 0, stream>>>(out_w, out_b, HSv, dec_out);
    k_lsm<<<TTGT, 1024, 0, stream>>>(dec_out);
}

// Round 7
// 850.153 us; speedup vs baseline: 2.5019x; 1.0850x over previous
//
#include <hip/hip_runtime.h>
#include <math.h>

#define VSZ 50000
#define HD 600
#define HHD 300
#define LATD 100
#define MLEN 50
#define TIN 48
#define TTGT 50
#define NBLK 75
#define NTHR 512
#define NTOT (NBLK*NTHR)
#define ESTR 640              // padded row stride (2560B)
#define SLOT_STRIDE 32        // ints; 128B between slots
#define SENTU 0x40000000u     // 2.0f — impossible GRU output (|h| < 1 strictly)

typedef __attribute__((ext_vector_type(4))) float f32x4;
typedef __attribute__((ext_vector_type(8))) short s16x8;

__device__ __forceinline__ float sigf(float x){ return 1.0f/(1.0f+__expf(-x)); }

// agent-scope (coherent-point) store: write-through past non-coherent L2s
__device__ __forceinline__ void stf(float* p, float v){
    __hip_atomic_store((unsigned int*)p, __float_as_uint(v),
                       __ATOMIC_RELAXED, __HIP_MEMORY_SCOPE_AGENT);
}
__device__ __forceinline__ void stu(float* p, unsigned v){
    __hip_atomic_store((unsigned int*)p, v,
                       __ATOMIC_RELAXED, __HIP_MEMORY_SCOPE_AGENT);
}
__device__ __forceinline__ int ldslot(const int* p){
    return __hip_atomic_load(p, __ATOMIC_RELAXED, __HIP_MEMORY_SCOPE_AGENT);
}
__device__ __forceinline__ void stslot(int* p, int v){
    __hip_atomic_store(p, v, __ATOMIC_RELAXED, __HIP_MEMORY_SCOPE_AGENT);
}

// uncached 16B load (bypasses L1+L2 -> MALL), waits completion inside
__device__ __forceinline__ f32x4 ld_unc16(const float* p){
    f32x4 r;
    asm volatile("global_load_dwordx4 %0, %1, off sc0 sc1\n\ts_waitcnt vmcnt(0)"
                 : "=v"(r) : "v"(p) : "memory");
    return r;
}
// poll a 16B chunk until no word equals the sentinel
__device__ __forceinline__ f32x4 poll16(const float* p){
    f32x4 r = ld_unc16(p);
    while (__float_as_uint(r[0])==SENTU || __float_as_uint(r[1])==SENTU ||
           __float_as_uint(r[2])==SENTU || __float_as_uint(r[3])==SENTU){
        __builtin_amdgcn_s_sleep(1);
        r = ld_unc16(p);
    }
    return r;
}

__device__ __forceinline__ void redu3(float&a,float&b,float&c){
    #pragma unroll
    for(int off=32;off;off>>=1){
        a+=__shfl_xor(a,off); b+=__shfl_xor(b,off); c+=__shfl_xor(c,off);
    }
}
__device__ __forceinline__ void redu6(float&a,float&b,float&c,float&d,float&e,float&f){
    #pragma unroll
    for(int off=32;off;off>>=1){
        a+=__shfl_xor(a,off); b+=__shfl_xor(b,off); c+=__shfl_xor(c,off);
        d+=__shfl_xor(d,off); e+=__shfl_xor(e,off); f+=__shfl_xor(f,off);
    }
}

// Two-level leader barrier (only 4 uses now: pre, latent x3)
__device__ __forceinline__ void gridbar(int* slots, int* flags, int e){
    asm volatile("s_waitcnt vmcnt(0)" ::: "memory");
    __syncthreads();
    const int tid = threadIdx.x;
    if (tid == 0) stslot(&slots[blockIdx.x*SLOT_STRIDE], e);
    if (blockIdx.x == 0){
        if (tid < NBLK){
            while (ldslot(&slots[tid*SLOT_STRIDE]) < e)
                __builtin_amdgcn_s_sleep(1);
        }
        __syncthreads();
        if (tid < NBLK) stslot(&flags[tid*SLOT_STRIDE], e);
    } else {
        if (tid == 0){
            while (ldslot(&flags[blockIdx.x*SLOT_STRIDE]) < e)
                __builtin_amdgcn_s_sleep(1);
        }
    }
    __syncthreads();
}

__global__ void k_init(int* sync_mem){
    int i = blockIdx.x*blockDim.x + threadIdx.x;
    if (i < 2*NBLK*SLOT_STRIDE) sync_mem[i] = 0;
}

__global__ void __launch_bounds__(NTHR) k_seq(
    const float* __restrict__ emb_enc, const float* __restrict__ emb_dec,
    const float* __restrict__ enc_wih_f, const float* __restrict__ enc_whh_f,
    const float* __restrict__ enc_bih_f, const float* __restrict__ enc_bhh_f,
    const float* __restrict__ enc_wih_b, const float* __restrict__ enc_whh_b,
    const float* __restrict__ enc_bih_b, const float* __restrict__ enc_bhh_b,
    const float* __restrict__ dec_wih_f, const float* __restrict__ dec_whh_f,
    const float* __restrict__ dec_bih_f, const float* __restrict__ dec_bhh_f,
    const float* __restrict__ dec_wih_b, const float* __restrict__ dec_whh_b,
    const float* __restrict__ dec_bih_b, const float* __restrict__ dec_bhh_b,
    const float* __restrict__ w_mean, const float* __restrict__ b_mean,
    const float* __restrict__ w_logv, const float* __restrict__ b_logv,
    const float* __restrict__ w_l2h, const float* __restrict__ b_l2h,
    const float* __restrict__ attn_w, const float* __restrict__ attn_b,
    const float* __restrict__ comb_w, const float* __restrict__ comb_b,
    const float* __restrict__ eps, const int* __restrict__ in_toks,
    const int* __restrict__ tgt_toks,
    float* __restrict__ GIf, float* __restrict__ ENCf,
    float* __restrict__ Zf, float* __restrict__ LATf, float* __restrict__ Mf,
    float* __restrict__ APREf, float* __restrict__ CPREf,
    float* __restrict__ HSs, float* __restrict__ HSv,
    float* __restrict__ out_mean, float* __restrict__ out_logv,
    int* slots, int* flags){

    __shared__ float h_lds[ESTR];
    __shared__ float o_lds[ESTR];
    __shared__ float s_lds[64];
    __shared__ float aw_lds[64];
    __shared__ float hv_lds[8];
    __shared__ float big_lds[HD*MLEN];  // encoder: ENC[50][600]; decoder: Mf[600][50]

    const int tid  = threadIdx.x;
    const int lane = tid & 63;
    const int wid  = tid >> 6;
    const int gtid = blockIdx.x*NTHR + tid;
    const int gw   = blockIdx.x*8 + wid;      // 0..599, == dir*HHD + k
    const int dir  = gw / HHD;
    const int k    = gw % HHD;
    int ep = 0;

    if (tid < ESTR-HD){ h_lds[HD+tid]=0.f; o_lds[HD+tid]=0.f; }

    // ---------------- PRE PHASE ----------------
    // sentinel-init all polled rows (ENC 0..47, HS 0..49)
    for (int idx=gtid; idx<TIN*HD; idx+=NTOT){
        int t=idx/HD, j=idx%HD;
        stu(&ENCf[(long)t*ESTR + j], SENTU);
    }
    for (int idx=gtid; idx<TTGT*HD; idx+=NTOT){
        int t=idx/HD, j=idx%HD;
        stu(&HSs[(long)t*ESTR + j], SENTU);
    }
    // GI: R1-exact bias-seeded single fmaf chain
    for (int idx=gtid; idx<TIN*1800; idx+=NTOT){
        int t=idx/1800, r=idx%1800, d=r/900, j=r%900;
        const float* w  = d ? enc_wih_b : enc_wih_f;
        const float* bi = d ? enc_bih_b : enc_bih_f;
        const float* x  = emb_enc + (long)in_toks[t]*HD;
        const float* wr = w + (long)j*HD;
        float acc = bi[j];
        for (int kk=0;kk<HD;kk+=4){
            float4 wv = *(const float4*)(wr+kk);
            float4 xv = *(const float4*)(x+kk);
            acc = fmaf(wv.x,xv.x,acc); acc = fmaf(wv.y,xv.y,acc);
            acc = fmaf(wv.z,xv.z,acc); acc = fmaf(wv.w,xv.w,acc);
        }
        stf(&GIf[idx], acc);
    }
    for (int idx=gtid; idx<TTGT*MLEN; idx+=NTOT){
        int t=idx/MLEN, a=idx%MLEN;
        int tok = t ? tgt_toks[t-1] : 1;
        const float* x  = emb_dec + (long)tok*HD;
        const float* wr = attn_w + (long)a*1200;
        float acc = attn_b[a];
        for (int kk=0;kk<HD;kk+=4){
            float4 wv = *(const float4*)(wr+kk);
            float4 xv = *(const float4*)(x+kk);
            acc = fmaf(wv.x,xv.x,acc); acc = fmaf(wv.y,xv.y,acc);
            acc = fmaf(wv.z,xv.z,acc); acc = fmaf(wv.w,xv.w,acc);
        }
        stf(&APREf[idx], acc);
    }
    for (int idx=gtid; idx<TTGT*HD; idx+=NTOT){
        int t=idx/HD, j=idx%HD;
        int tok = t ? tgt_toks[t-1] : 1;
        const float* x  = emb_dec + (long)tok*HD;
        const float* wr = comb_w + (long)j*1200;
        float acc = comb_b[j];
        for (int kk=0;kk<HD;kk+=4){
            float4 wv = *(const float4*)(wr+kk);
            float4 xv = *(const float4*)(x+kk);
            acc = fmaf(wv.x,xv.x,acc); acc = fmaf(wv.y,xv.y,acc);
            acc = fmaf(wv.z,xv.z,acc); acc = fmaf(wv.w,xv.w,acc);
        }
        stf(&CPREf[idx], acc);
    }
    gridbar(slots, flags, ++ep);   // barrier 1: sentinels + GI/APRE/CPRE visible

    // ---------------- ENCODER (48 steps, data-poll sync, no barriers) ------
    {
        const float* whh = dir ? enc_whh_b : enc_whh_f;
        const float* bhh = dir ? enc_bhh_b : enc_bhh_f;
        float wr_[5], wz_[5], wn_[5];
        #pragma unroll
        for (int i=0;i<5;i++){
            int k2 = lane + 64*i;
            bool ok = k2 < HHD;
            wr_[i] = ok ? whh[(long)k*HHD + k2] : 0.f;
            wz_[i] = ok ? whh[(long)(HHD+k)*HHD + k2] : 0.f;
            wn_[i] = ok ? whh[(long)(2*HHD+k)*HHD + k2] : 0.f;
        }
        const float bhr = bhh[k], bhz = bhh[HHD+k], bhn = bhh[2*HHD+k];
        float gr=0, gz=0, gn=0;
        if (lane < TIN){
            const float* g = GIf + (long)lane*1800 + dir*900;   // cached, post-bar
            gr = g[k]; gz = g[HHD+k]; gn = g[2*HHD+k];
        }
        for (int t=0; t<TIN; t++){
            if (t){
                if (tid < HD/4)
                    *(f32x4*)&h_lds[4*tid] = poll16(&ENCf[(long)(t-1)*ESTR + 4*tid]);
            } else {
                h_lds[tid] = 0.f;
                if (tid < HD-NTHR) h_lds[NTHR+tid] = 0.f;
            }
            __syncthreads();
            if (t){   // archive row t-1 into block-local ENC copy
                big_lds[(long)(t-1)*HD + tid] = h_lds[tid];
                if (tid < HD-NTHR) big_lds[(long)(t-1)*HD + NTHR + tid] = h_lds[NTHR+tid];
            }
            float sr=0, sz=0, sn=0;
            #pragma unroll
            for (int i=0;i<5;i++){
                float hv = h_lds[dir*HHD + lane + 64*i];
                sr = fmaf(wr_[i], hv, sr);
                sz = fmaf(wz_[i], hv, sz);
                sn = fmaf(wn_[i], hv, sn);
            }
            redu3(sr, sz, sn);
            float grt=__shfl(gr,t), gzt=__shfl(gz,t), gnt=__shfl(gn,t);
            if (lane==0){
                float r = sigf(grt + sr + bhr);
                float z = sigf(gzt + sz + bhz);
                float n = tanhf(gnt + r*(sn + bhn));
                float hp = h_lds[gw];
                hv_lds[wid] = (1.f-z)*n + z*hp;
            }
            __syncthreads();
            if (tid < 8) stf(&ENCf[(long)t*ESTR + blockIdx.x*8 + tid], hv_lds[tid]);
        }
        // pull final row 47 (needed for latent + decoder t=0)
        if (tid < HD/4)
            *(f32x4*)&h_lds[4*tid] = poll16(&ENCf[(long)(TIN-1)*ESTR + 4*tid]);
        __syncthreads();
        big_lds[(long)(TIN-1)*HD + tid] = h_lds[tid];
        if (tid < HD-NTHR) big_lds[(long)(TIN-1)*HD + NTHR + tid] = h_lds[NTHR+tid];
        // rows 48,49 are zeros
        big_lds[TIN*HD + tid] = 0.f;
        big_lds[TIN*HD + NTHR + tid] = 0.f;
        if (tid < 2*HD - 2*NTHR) big_lds[TIN*HD + 2*NTHR + tid] = 0.f;
        __syncthreads();
    }

    // ---------------- LATENT (mean/logv/Z fused; ENC from LDS) -------------
    for (int idx=gtid; idx<MLEN*LATD; idx+=NTOT){
        int i=idx/LATD, l=idx%LATD;
        const float* e = &big_lds[(long)i*HD];
        const float* wmr = w_mean + (long)l*HD;
        float am = b_mean[l];
        for (int kk=0;kk<HD;kk+=4){
            f32x4 wv = *(const f32x4*)(wmr+kk);
            f32x4 ev = *(const f32x4*)(e+kk);
            am = fmaf(wv[0],ev[0],am); am = fmaf(wv[1],ev[1],am);
            am = fmaf(wv[2],ev[2],am); am = fmaf(wv[3],ev[3],am);
        }
        const float* wlr = w_logv + (long)l*HD;
        float al = b_logv[l];
        for (int kk=0;kk<HD;kk+=4){
            f32x4 wv = *(const f32x4*)(wlr+kk);
            f32x4 ev = *(const f32x4*)(e+kk);
            al = fmaf(wv[0],ev[0],al); al = fmaf(wv[1],ev[1],al);
            al = fmaf(wv[2],ev[2],al); al = fmaf(wv[3],ev[3],al);
        }
        out_mean[idx] = am;
        out_logv[idx] = al;
        stf(&Zf[idx], eps[idx]*__expf(0.5f*al) + am);
    }
    gridbar(slots, flags, ++ep);   // barrier 2: Z visible
    for (int idx=gtid; idx<MLEN*HD; idx+=NTOT){
        int i=idx/HD, j=idx%HD;
        const float* zr = Zf + (long)i*LATD;
        const float* wr = w_l2h + (long)j*LATD;
        float acc = b_l2h[j];
        for (int kk=0;kk<LATD;kk+=4){
            float4 wv = *(const float4*)(wr+kk);
            float4 zv = *(const float4*)(zr+kk);
            acc = fmaf(wv.x,zv.x,acc); acc = fmaf(wv.y,zv.y,acc);
            acc = fmaf(wv.z,zv.z,acc); acc = fmaf(wv.w,zv.w,acc);
        }
        stf(&LATf[idx], acc);
    }
    gridbar(slots, flags, ++ep);   // barrier 3: LAT visible
    // Mf j-major: Mf[j*MLEN + i] = dot(comb_w[j,600:], LAT[i,:])
    for (int idx=gtid; idx<MLEN*HD; idx+=NTOT){
        int j=idx/MLEN, i=idx%MLEN;
        const float* wr = comb_w + (long)j*1200 + HD;
        const float* lr = LATf + (long)i*HD;
        float acc = 0.f;
        for (int kk=0;kk<HD;kk+=4){
            float4 wv = *(const float4*)(wr+kk);
            float4 lv = *(const float4*)(lr+kk);
            acc = fmaf(wv.x,lv.x,acc); acc = fmaf(wv.y,lv.y,acc);
            acc = fmaf(wv.z,lv.z,acc); acc = fmaf(wv.w,lv.w,acc);
        }
        stf(&Mf[idx], acc);
    }
    gridbar(slots, flags, ++ep);   // barrier 4: M visible

    // ---------------- DECODER (50 steps, data-poll sync, no barriers) ------
    {
        // Mf -> LDS (overwrites ENC copy; guarded by barrier 4 + syncthreads below)
        for (int idx=tid; idx<HD*MLEN/4; idx+=NTHR)
            *(f32x4*)&big_lds[4*idx] = *(const f32x4*)&Mf[4*idx];

        const float* wih = dir ? dec_wih_b : dec_wih_f;
        const float* bih = dir ? dec_bih_b : dec_bih_f;
        const float* whh = dir ? dec_whh_b : dec_whh_f;
        const float* bhh = dir ? dec_bhh_b : dec_bhh_f;
        float ur[10], uz[10], un[10];
        #pragma unroll
        for (int i=0;i<10;i++){
            int k2 = lane + 64*i;
            bool ok = k2 < HD;
            ur[i] = ok ? wih[(long)k*HD + k2] : 0.f;
            uz[i] = ok ? wih[(long)(HHD+k)*HD + k2] : 0.f;
            un[i] = ok ? wih[(long)(2*HHD+k)*HD + k2] : 0.f;
        }
        float vr[5], vz[5], vn[5];
        #pragma unroll
        for (int i=0;i<5;i++){
            int k2 = lane + 64*i;
            bool ok = k2 < HHD;
            vr[i] = ok ? whh[(long)k*HHD + k2] : 0.f;
            vz[i] = ok ? whh[(long)(HHD+k)*HHD + k2] : 0.f;
            vn[i] = ok ? whh[(long)(2*HHD+k)*HHD + k2] : 0.f;
        }
        const float bir = bih[k], biz = bih[HHD+k], bin_ = bih[2*HHD+k];
        const float bhr = bhh[k], bhz = bhh[HHD+k], bhn = bhh[2*HHD+k];

        for (int t=0; t<TTGT; t++){
            if (t){
                if (tid < HD/4)
                    *(f32x4*)&h_lds[4*tid] = poll16(&HSs[(long)(t-1)*ESTR + 4*tid]);
            }
            // t==0: h_lds still holds ENC row 47 from encoder epilogue
            float cp0 = CPREf[(long)t*HD + tid];
            float cp1 = (tid < HD-NTHR) ? CPREf[(long)t*HD + NTHR + tid] : 0.f;
            __syncthreads();
            // attention scores (replicated per block)
            for (int a=wid; a<MLEN; a+=8){
                const float* arow = attn_w + (long)a*1200 + HD;
                float acc = 0.f;
                #pragma unroll
                for (int i=0;i<10;i++){
                    int kk = lane + 64*i;
                    if (kk < HD) acc = fmaf(arow[kk], h_lds[kk], acc);
                }
                #pragma unroll
                for (int off=32;off;off>>=1) acc += __shfl_xor(acc,off);
                if (lane==0) s_lds[a] = acc + APREf[t*MLEN + a];
            }
            __syncthreads();
            // softmax — R1-exact serial form (one thread)
            if (tid==0){
                float m = -1e30f;
                for (int a=0;a<MLEN;a++) m = fmaxf(m, s_lds[a]);
                float sum = 0.f;
                for (int a=0;a<MLEN;a++){ float e = __expf(s_lds[a]-m); aw_lds[a]=e; sum+=e; }
                float inv = 1.f/sum;
                for (int a=0;a<MLEN;a++) aw_lds[a] *= inv;
            }
            __syncthreads();
            // o = relu(CPRE + M^T aw) — Mf from LDS, i ascending
            {
                float acc = cp0;
                const float* mr = &big_lds[tid*MLEN];
                #pragma unroll
                for (int i=0;i<MLEN;i++) acc = fmaf(mr[i], aw_lds[i], acc);
                o_lds[tid] = fmaxf(acc, 0.f);
                if (tid < HD-NTHR){
                    float acc2 = cp1;
                    const float* mr2 = &big_lds[(NTHR+tid)*MLEN];
                    #pragma unroll
                    for (int i=0;i<MLEN;i++) acc2 = fmaf(mr2[i], aw_lds[i], acc2);
                    o_lds[NTHR+tid] = fmaxf(acc2, 0.f);
                }
            }
            __syncthreads();
            // GRU cells
            float ar=0,az=0,an=0, hr=0,hz=0,hn=0;
            #pragma unroll
            for (int i=0;i<10;i++){
                float ov = o_lds[lane + 64*i];
                ar = fmaf(ur[i], ov, ar);
                az = fmaf(uz[i], ov, az);
                an = fmaf(un[i], ov, an);
            }
            #pragma unroll
            for (int i=0;i<5;i++){
                float hv = h_lds[dir*HHD + lane + 64*i];
                hr = fmaf(vr[i], hv, hr);
                hz = fmaf(vz[i], hv, hz);
                hn = fmaf(vn[i], hv, hn);
            }
            redu6(ar,az,an,hr,hz,hn);
            if (lane==0){
                float r = sigf(ar + bir + hr + bhr);
                float zg = sigf(az + biz + hz + bhz);
                float n = tanhf(an + bin_ + r*(hn + bhn));
                hv_lds[wid] = (1.f-zg)*n + zg*h_lds[gw];
            }
            __syncthreads();
            if (tid < 8){
                float hnew = hv_lds[tid];
                stf(&HSs[(long)t*ESTR + blockIdx.x*8 + tid], hnew);
                HSv[(long)t*HD + blockIdx.x*8 + tid] = hnew;   // for k_vocab
            }
        }
    }
}

// ---------------- vocab projection: bf16 MFMA, fused f32->bf16 ----------------
__device__ __forceinline__ s16x8 pack8(const float* __restrict__ p){
    s16x8 r;
    #pragma unroll
    for (int i=0;i<8;i++){
        unsigned u = __float_as_uint(p[i]);
        r[i] = (short)((u + 0x7fffu + ((u>>16)&1u)) >> 16);
    }
    return r;
}

__global__ void __launch_bounds__(256) k_vocab(const float* __restrict__ out_w,
        const float* __restrict__ out_b, const float* __restrict__ HS,
        float* __restrict__ logits){
    int lane = threadIdx.x & 63, wid = threadIdx.x >> 6;
    int vbase = blockIdx.x*64 + wid*16;
    int arow  = vbase + (lane & 15);
    int kg    = (lane >> 4) * 8;
    bool aok  = arow < VSZ;
    const float* ap = out_w + (long)(aok ? arow : 0) * HD;
    int t0 = lane & 15;
    f32x4 acc0 = {0,0,0,0}, acc1 = acc0, acc2 = acc0, acc3 = acc0;
    const s16x8 zf = (s16x8)0;

    for (int ks=0; ks<19; ks++){
        int kb = ks*32 + kg;
        bool kok = kb < HD;
        s16x8 a = (aok && kok) ? pack8(ap + kb) : zf;
        s16x8 b0 = kok              ? pack8(HS + (long)(t0     )*HD + kb) : zf;
        s16x8 b1 = kok              ? pack8(HS + (long)(t0 + 16)*HD + kb) : zf;
        s16x8 b2 = kok              ? pack8(HS + (long)(t0 + 32)*HD + kb) : zf;
        s16x8 b3 = (kok && t0 < 2)  ? pack8(HS + (long)(t0 + 48)*HD + kb) : zf;
        acc0 = __builtin_amdgcn_mfma_f32_16x16x32_bf16(a, b0, acc0, 0,0,0);
        acc1 = __builtin_amdgcn_mfma_f32_16x16x32_bf16(a, b1, acc1, 0,0,0);
        acc2 = __builtin_amdgcn_mfma_f32_16x16x32_bf16(a, b2, acc2, 0,0,0);
        acc3 = __builtin_amdgcn_mfma_f32_16x16x32_bf16(a, b3, acc3, 0,0,0);
    }

    int vst = vbase + (lane>>4)*4;
    float bb[4];
    #pragma unroll
    for (int r=0;r<4;r++) bb[r] = (vst+r < VSZ) ? out_b[vst+r] : 0.f;
    #pragma unroll
    for (int f=0; f<4; f++){
        int t = t0 + 16*f;
        if (t >= TTGT) continue;
        const f32x4 acc = f==0?acc0 : f==1?acc1 : f==2?acc2 : acc3;
        float* rowp = logits + (long)t*VSZ;
        #pragma unroll
        for (int r=0;r<4;r++){
            int v = vst + r;
            if (v < VSZ) rowp[v] = acc[r] + bb[r];
        }
    }
}

// in-place log-softmax per step row
__global__ void __launch_bounds__(1024) k_lsm(float* __restrict__ logits){
    __shared__ float red[16];
    __shared__ float sm, sl;
    long t = blockIdx.x;
    float* row = logits + t*VSZ;
    int tid = threadIdx.x, lane = tid&63, w = tid>>6;
    float m = -1e30f;
    for (int v=tid; v<VSZ; v+=1024) m = fmaxf(m, row[v]);
    #pragma unroll
    for (int off=32;off;off>>=1) m = fmaxf(m, __shfl_xor(m,off));
    if (lane==0) red[w] = m;
    __syncthreads();
    if (tid==0){ float mm=red[0]; for (int i=1;i<16;i++) mm=fmaxf(mm,red[i]); sm=mm; }
    __syncthreads();
    float mx = sm;
    float s = 0.f;
    for (int v=tid; v<VSZ; v+=1024) s += __expf(row[v]-mx);
    #pragma unroll
    for (int off=32;off;off>>=1) s += __shfl_xor(s,off);
    __syncthreads();
    if (lane==0) red[w] = s;
    __syncthreads();
    if (tid==0){ float ss=0.f; for (int i=0;i<16;i++) ss+=red[i]; sl = logf(ss); }
    __syncthreads();
    float lg = sl;
    for (int v=tid; v<VSZ; v+=1024) row[v] = row[v] - mx - lg;
}

extern "C" void kernel_launch(void* const* d_in, const int* in_sizes, int n_in,
                              void* d_out, int out_size, void* d_ws, size_t ws_size,
                              hipStream_t stream) {
    const float* emb_enc   = (const float*)d_in[0];
    const float* emb_dec   = (const float*)d_in[1];
    const float* enc_wih_f = (const float*)d_in[2];
    const float* enc_whh_f = (const float*)d_in[3];
    const float* enc_bih_f = (const float*)d_in[4];
    const float* enc_bhh_f = (const float*)d_in[5];
    const float* enc_wih_b = (const float*)d_in[6];
    const float* enc_whh_b = (const float*)d_in[7];
    const float* enc_bih_b = (const float*)d_in[8];
    const float* enc_bhh_b = (const float*)d_in[9];
    const float* dec_wih_f = (const float*)d_in[10];
    const float* dec_whh_f = (const float*)d_in[11];
    const float* dec_bih_f = (const float*)d_in[12];
    const float* dec_bhh_f = (const float*)d_in[13];
    const float* dec_wih_b = (const float*)d_in[14];
    const float* dec_whh_b = (const float*)d_in[15];
    const float* dec_bih_b = (const float*)d_in[16];
    const float* dec_bhh_b = (const float*)d_in[17];
    const float* w_mean    = (const float*)d_in[18];
    const float* b_mean    = (const float*)d_in[19];
    const float* w_logv    = (const float*)d_in[20];
    const float* b_logv    = (const float*)d_in[21];
    const float* w_l2h     = (const float*)d_in[22];
    const float* b_l2h     = (const float*)d_in[23];
    const float* attn_w    = (const float*)d_in[24];
    const float* attn_b    = (const float*)d_in[25];
    const float* comb_w    = (const float*)d_in[26];
    const float* comb_b    = (const float*)d_in[27];
    const float* out_w     = (const float*)d_in[28];
    const float* out_b     = (const float*)d_in[29];
    const float* eps       = (const float*)d_in[30];
    const int*   in_toks   = (const int*)d_in[31];
    const int*   tgt_toks  = (const int*)d_in[32];

    float* ws = (float*)d_ws;                  // all offsets 128B-aligned
    float* GIf   = ws;                         // 48*1800 = 86400
    float* ENCf  = ws + 86400;                 // 50*640  = 32000
    float* Zf    = ws + 118400;                // 5024
    float* LATf  = ws + 123424;                // 30016
    float* Mf    = ws + 153440;                // 30016 ([j][i], stride 50)
    float* APREf = ws + 183456;                // 2528
    float* CPREf = ws + 185984;                // 30016
    float* HSs   = ws + 216000;                // 50*640 = 32000 (padded state)
    float* HSv   = ws + 248000;                // 50*600 = 30016 (for k_vocab)
    int*   slots = (int*)(ws + 278016);        // 75*32 ints
    int*   flags = (int*)(ws + 280416);        // 75*32 ints

    float* dec_out  = (float*)d_out;
    float* out_mean = dec_out + 2500000;
    float* out_logv = dec_out + 2505000;

    k_init<<<(2*NBLK*SLOT_STRIDE + 255)/256, 256, 0, stream>>>((int*)(ws + 278016));

    k_seq<<<NBLK, NTHR, 0, stream>>>(
        emb_enc, emb_dec,
        enc_wih_f, enc_whh_f, enc_bih_f, enc_bhh_f,
        enc_wih_b, enc_whh_b, enc_bih_b, enc_bhh_b,
        dec_wih_f, dec_whh_f, dec_bih_f, dec_bhh_f,
        dec_wih_b, dec_whh_b, dec_bih_b, dec_bhh_b,
        w_mean, b_mean, w_logv, b_logv, w_l2h, b_l2h,
        attn_w, attn_b, comb_w, comb_b,
        eps, in_toks, tgt_toks,
        GIf, ENCf, Zf, LATf, Mf, APREf, CPREf, HSs, HSv,
        out_mean, out_logv, slots, flags);

    k_vocab<<<(VSZ + 63)/64, 256, 0, stream>>>(out_w, out_b, HSv, dec_out);
    k_lsm<<<TTGT, 1024, 0, stream>>>(dec_out);
}